// Round 15
// baseline (1766.787 us; speedup 1.0000x reference)
//
#include <hip/hip_runtime.h>
#include <math.h>

#define UNITS   128
#define NRBF    10
#define SBF     9
#define NLAYERS 3
#define NELEM   95
#define NTOTAL  60000
#define NLOCAL  50000
#define NGHOST  10000
#define NEDGE   250000
#define NTRIPLE 1000000
#define CUTOFF  5.0f
#define TBCUT   4.0f
#define PI_F    3.14159265358979323846f
#define FSTR    424   // feat row stride in ushorts: 13 kb * 32 + 8 pad
#define MEDGE   64    // edges per gated block

typedef __attribute__((ext_vector_type(8))) short short8;
typedef __attribute__((ext_vector_type(4))) float f32x4;

__device__ __forceinline__ float sigm(float x){ return 1.0f/(1.0f+__expf(-x)); }
__device__ __forceinline__ float polycut(float r){
    float q = r*(1.0f/TBCUT);
    float q2 = q*q, q3 = q2*q;
    float p = 1.0f - 6.0f*q2*q3 + 15.0f*q2*q2 - 10.0f*q3;
    return (r <= TBCUT) ? p : 0.0f;
}
__device__ __forceinline__ ushort f2bf(float x){
    unsigned u = __float_as_uint(x);
    unsigned r = (u + 0x7fffu + ((u>>16)&1u)) >> 16;
    return (ushort)r;
}
__device__ __forceinline__ float bf2f(ushort h){
    return __uint_as_float(((unsigned)h) << 16);
}
__device__ __forceinline__ f32x4 splat4(float x){ f32x4 v = {x,x,x,x}; return v; }
__device__ __forceinline__ float gatef(float xm, float xg){
    float d = (1.0f+__expf(-xm))*(1.0f+__expf(-xg));
    return xm*__builtin_amdgcn_rcpf(d);
}

// ---------------- edge geometry + rbf ----------------
__global__ void k_edge_geom(const float* __restrict__ pos, const float* __restrict__ cell,
                            const float* __restrict__ pbc, const int* __restrict__ src,
                            const int* __restrict__ dst, const int* __restrict__ batch,
                            float* __restrict__ evec, float* __restrict__ elen,
                            float* __restrict__ rbf0){
    int e = blockIdx.x*blockDim.x + threadIdx.x;
    if (e >= NEDGE) return;
    int s = src[e], d = dst[e];
    int b = batch[s];
    const float* C = cell + b*9;
    float p0 = pbc[e*3+0], p1 = pbc[e*3+1], p2 = pbc[e*3+2];
    float vx = pos[s*3+0] - (pos[d*3+0] + p0*C[0] + p1*C[3] + p2*C[6]);
    float vy = pos[s*3+1] - (pos[d*3+1] + p0*C[1] + p1*C[4] + p2*C[7]);
    float vz = pos[s*3+2] - (pos[d*3+2] + p0*C[2] + p1*C[5] + p2*C[8]);
    float r = sqrtf(vx*vx + vy*vy + vz*vz);
    evec[e*3+0] = vx; evec[e*3+1] = vy; evec[e*3+2] = vz;
    elen[e] = r;
    #pragma unroll
    for (int i = 0; i < NRBF; i++){
        float mu = (CUTOFF/(NRBF-1))*i;
        float dm = r - mu;
        rbf0[e*NRBF + i] = __expf(-dm*dm*2.0f);
    }
}

// ---------------- atom embedding gather (f32 + NTOTAL bf16 mirror) ----------------
__global__ void k_embed(const int* __restrict__ anum, const float* __restrict__ embw,
                        float* __restrict__ A, ushort* __restrict__ Ah){
    int t = blockIdx.x*blockDim.x + threadIdx.x;
    if (t >= NTOTAL*32) return;
    int a = t >> 5, q = t & 31;
    float4 v = ((const float4*)embw)[anum[a]*32 + q];
    ((float4*)A)[t] = v;
    ushort4 h;
    h.x = f2bf(v.x); h.y = f2bf(v.y); h.z = f2bf(v.z); h.w = f2bf(v.w);
    ((ushort4*)Ah)[t] = h;
}

// ---------------- pack main gated-MLP weights: [L][mat:4][kb:12][nt:8][lane:64][j:8] ----------------
__global__ void k_pack_w(const float* __restrict__ gewm, const float* __restrict__ gewg,
                         const float* __restrict__ gawm, const float* __restrict__ gawg,
                         ushort* __restrict__ wp){
    int t = blockIdx.x*blockDim.x + threadIdx.x;
    if (t >= 3*4*12*8*64) return;
    int lane = t & 63;
    int nt   = (t>>6) & 7;
    int rest = t >> 9;
    int kb   = rest % 12;
    int r2   = rest / 12;
    int mat  = r2 & 3;
    int L    = r2 >> 2;
    const float* src;
    if      (mat == 0) src = gewm;
    else if (mat == 1) src = gewg;
    else if (mat == 2) src = gawm;
    else               src = gawg;
    src += (size_t)L*384*128;
    int n = nt*16 + (lane & 15);
    int kbase = kb*32 + (lane>>4)*8;
    ushort* dst = wp + (size_t)t*8;
    #pragma unroll
    for (int j = 0; j < 8; j++) dst[j] = f2bf(src[(size_t)(kbase+j)*128 + n]);
}

// ---------------- pack kb12 ext weights ----------------
__global__ void k_pack_ext(const float* __restrict__ gewm, const float* __restrict__ gewg,
                           const float* __restrict__ tbg, const float* __restrict__ encw,
                           ushort* __restrict__ wext){
    int t = blockIdx.x*blockDim.x + threadIdx.x;
    if (t >= 3*2*512) return;
    int lane = t & 63;
    int nt   = (t>>6) & 7;
    int mat  = (t>>9) & 1;
    int L    = t >> 10;
    const float* W = ((mat==0)? gewm : gewg) + (size_t)L*384*128;
    const float* tg = tbg + (size_t)L*SBF*UNITS;
    int n = nt*16 + (lane & 15);
    ushort* dst = wext + (size_t)t*8;
    #pragma unroll
    for (int j = 0; j < 8; j++){
        int k = (lane>>4)*8 + j;
        float v = 0.0f;
        if (k >= 10 && k <= 18){
            int s = k - 10;
            for (int kk = 0; kk < 128; kk++)
                v = fmaf(tg[s*UNITS+kk], W[(size_t)(256+kk)*128 + n], v);
        } else if (k < 10 && L == 0){
            for (int kk = 0; kk < 128; kk++)
                v = fmaf(encw[k*UNITS+kk], W[(size_t)(256+kk)*128 + n], v);
        }
        dst[j] = f2bf(v);
    }
}

// ---------------- pack aux B mats: el_e, el_a, tbgate ----------------
__global__ void k_pack_aux(const float* __restrict__ elew, const float* __restrict__ elaw,
                           const float* __restrict__ tbg, ushort* __restrict__ waux){
    int t = blockIdx.x*blockDim.x + threadIdx.x;
    if (t >= 3*3*512) return;
    int lane = t & 63;
    int nt   = (t>>6) & 7;
    int rest = t >> 9;
    int mat  = rest % 3;
    int L    = rest / 3;
    int n = nt*16 + (lane & 15);
    ushort* dst = waux + (size_t)t*8;
    #pragma unroll
    for (int j = 0; j < 8; j++){
        int k = (lane>>4)*8 + j;
        float v = 0.0f;
        if (mat == 0){ if (k < 10) v = elew[(size_t)L*NRBF*UNITS + k*UNITS + n]; }
        else if (mat == 1){ if (k < 10) v = elaw[(size_t)L*NRBF*UNITS + k*UNITS + n]; }
        else { if (k >= 10 && k <= 18) v = tbg[(size_t)L*SBF*UNITS + (k-10)*UNITS + n]; }
        dst[j] = f2bf(v);
    }
}

// ---------------- pack enc B mat (E0 via MFMA, L0 only) ----------------
__global__ void k_pack_encB(const float* __restrict__ encw, ushort* __restrict__ wencb){
    int t = blockIdx.x*blockDim.x + threadIdx.x;
    if (t >= 512) return;
    int lane = t & 63;
    int nt   = t >> 6;
    int n = nt*16 + (lane & 15);
    ushort* dst = wencb + (size_t)t*8;
    #pragma unroll
    for (int j = 0; j < 8; j++){
        int k = (lane>>4)*8 + j;
        float v = (k < 10) ? encw[k*UNITS + n] : 0.0f;
        dst[j] = f2bf(v);
    }
}

// ---------------- bias totals ----------------
__global__ void k_pack_bias(const float* __restrict__ gewm, const float* __restrict__ gewg,
                            const float* __restrict__ gebm, const float* __restrict__ gebg,
                            const float* __restrict__ tbb, const float* __restrict__ encb,
                            float* __restrict__ btot){
    int t = blockIdx.x*blockDim.x + threadIdx.x;
    if (t >= 3*2*128) return;
    int n = t & 127;
    int mat = (t>>7) & 1;
    int L = t >> 8;
    const float* W = ((mat==0)? gewm : gewg) + (size_t)L*384*128;
    const float* be = ((mat==0)? gebm : gebg) + (size_t)L*UNITS;
    const float* tb = tbb + (size_t)L*UNITS;
    float v = be[n];
    for (int kk = 0; kk < 128; kk++){
        float f = tb[kk];
        if (L == 0) f += encb[kk];
        v = fmaf(f, W[(size_t)(256+kk)*128 + n], v);
    }
    btot[t] = v;
}

// ---------------- per-layer: atom sbf mlp + seed aggOut + bf16 mirror ----------------
__global__ void k_tb_mlp(const float* __restrict__ Fin, const float* __restrict__ W,
                         const float* __restrict__ b, float* __restrict__ out,
                         float* __restrict__ aggOut, ushort* __restrict__ Ah){
    int a = blockIdx.x*blockDim.x + threadIdx.x;
    if (a >= NLOCAL) return;
    float acc[SBF];
    #pragma unroll
    for (int s = 0; s < SBF; s++) acc[s] = b[s];
    const float4* row4 = (const float4*)(Fin + (size_t)a*UNITS);
    float4* agg4 = (float4*)(aggOut + (size_t)a*UNITS);
    ushort4* ah4 = (ushort4*)(Ah + (size_t)a*UNITS);
    for (int k4 = 0; k4 < 32; k4++){
        float4 v = row4[k4];
        agg4[k4] = v;
        ushort4 h;
        h.x = f2bf(v.x); h.y = f2bf(v.y); h.z = f2bf(v.z); h.w = f2bf(v.w);
        ah4[k4] = h;
        const float* w = W + (k4*4)*SBF;
        #pragma unroll
        for (int s = 0; s < SBF; s++){
            acc[s] = fmaf(v.x, w[s],        acc[s]);
            acc[s] = fmaf(v.y, w[s+SBF],    acc[s]);
            acc[s] = fmaf(v.z, w[s+2*SBF],  acc[s]);
            acc[s] = fmaf(v.w, w[s+3*SBF],  acc[s]);
        }
    }
    #pragma unroll
    for (int s = 0; s < SBF; s++) out[a*SBF + s] = sigm(acc[s]);
}

// ---------------- triples CSR build (one-time, layer-independent) ----------------
// pass 1: histogram of valid triples per ij edge
__global__ void k_triple_hist(const float* __restrict__ elen, const int* __restrict__ tbi,
                              int* __restrict__ hist){
    int t = blockIdx.x*blockDim.x + threadIdx.x;
    if (t >= NTRIPLE) return;
    int ij = tbi[2*t], ik = tbi[2*t+1];
    if (polycut(elen[ij])*polycut(elen[ik]) != 0.0f)
        atomicAdd(&hist[ij], 1);
}
// exclusive scan over NEDGE bins -> toff (NEDGE+1) and cursor copy
__global__ void k_scan(const int* __restrict__ hist, int* __restrict__ toff,
                       int* __restrict__ curs){
    __shared__ int part[256];
    int tid = threadIdx.x;
    const int chunk = (NEDGE + 255)/256;
    int beg = tid*chunk, end = min(beg+chunk, NEDGE);
    int s = 0;
    for (int i = beg; i < end; i++) s += hist[i];
    part[tid] = s;
    __syncthreads();
    for (int off = 1; off < 256; off <<= 1){
        int v = (tid >= off) ? part[tid-off] : 0;
        __syncthreads();
        part[tid] += v;
        __syncthreads();
    }
    int base = (tid == 0) ? 0 : part[tid-1];
    for (int i = beg; i < end; i++){
        toff[i] = base; curs[i] = base; base += hist[i];
    }
    if (tid == 255) toff[NEDGE] = base;
}
// pass 2: full geometry, scatter into CSR slots
__global__ void k_triple_scatter(const float* __restrict__ evec, const float* __restrict__ elen,
                                 const int* __restrict__ esrc, const int* __restrict__ tbi,
                                 int* __restrict__ curs, int* __restrict__ t_ka,
                                 float* __restrict__ t_cf){
    int t = blockIdx.x*blockDim.x + threadIdx.x;
    if (t >= NTRIPLE) return;
    int ij = tbi[2*t], ik = tbi[2*t+1];
    float rij = elen[ij], rik = elen[ik];
    float cc = polycut(rij)*polycut(rik);
    if (cc == 0.0f) return;
    float ax = evec[ij*3+0], ay = evec[ij*3+1], az = evec[ij*3+2];
    float bx = evec[ik*3+0], by = evec[ik*3+1], bz = evec[ik*3+2];
    float dot = ax*bx + ay*by + az*bz;
    float c = dot/(rij*rik + 1e-12f);
    c = fminf(fmaxf(c, -1.0f + 1e-7f), 1.0f - 1e-7f);
    float a0 = 1.0f, a1 = c, a2 = 2.0f*c*c - 1.0f;
    float x = rik*(PI_F/TBCUT);
    float s1, c1;
    __sincosf(x, &s1, &c1);
    float s2 = 2.0f*s1*c1;
    float s3 = s1*(3.0f - 4.0f*s1*s1);
    float inv = 1.0f/(rik + 1e-6f);
    float r0 = s1*inv, r1 = s2*inv, r2 = s3*inv;
    int pos = atomicAdd(&curs[ij], 1);
    t_ka[pos] = esrc[ik];
    float* d = t_cf + (size_t)pos*SBF;
    d[0] = r0*a0*cc; d[1] = r0*a1*cc; d[2] = r0*a2*cc;
    d[3] = r1*a0*cc; d[4] = r1*a1*cc; d[5] = r1*a2*cc;
    d[6] = r2*a0*cc; d[7] = r2*a1*cc; d[8] = r2*a2*cc;
}

// ---------------- fused per-layer gated blocks (ge + ga), all-MFMA ----------------
// R12-proven config: 64 edges/block, 512 threads, src_s/dst_s index cache in LDS.
// ENC/GM/STORE are COMPILE-TIME (R14 runtime enc machinery cost all layers +4 VGPR accs).
// tb(9) per edge computed INLINE from triples CSR (avg ~0.2 triples/edge) -> no tbout
// buffer, no per-layer memset/apply dispatches. Coalesced Eh writeback. NO launch_bounds.
template<int ENC, int GM, int STORE>
__global__
void k_gated_fused(const ushort* __restrict__ Ah, const int* __restrict__ gmap,
                   ushort* __restrict__ Eh,
                   const int* __restrict__ esrc, const int* __restrict__ edst,
                   const float* __restrict__ rbf0,
                   const int* __restrict__ toff, const int* __restrict__ t_ka,
                   const float* __restrict__ t_cf, const float* __restrict__ amlp,
                   const ushort* __restrict__ Wem, const ushort* __restrict__ Weg,
                   const ushort* __restrict__ Wam, const ushort* __restrict__ Wag,
                   const ushort* __restrict__ WxM, const ushort* __restrict__ WxG,
                   const ushort* __restrict__ Ble, const ushort* __restrict__ Bla,
                   const ushort* __restrict__ Bte, const ushort* __restrict__ Benc,
                   const float* __restrict__ btm, const float* __restrict__ btg,
                   const float* __restrict__ bam, const float* __restrict__ bag,
                   const float* __restrict__ tbb, const float* __restrict__ eleb,
                   const float* __restrict__ elab, const float* __restrict__ encb,
                   float* __restrict__ agg){
    __shared__ __align__(16) ushort feat_s[MEDGE*FSTR];
    __shared__ int src_s[MEDGE];
    __shared__ int dst_s[MEDGE];

    const int tid = threadIdx.x;
    const int e0  = blockIdx.x*MEDGE;

    if (tid < MEDGE){
        int e = min(e0 + tid, NEDGE-1);
        src_s[tid] = esrc[e];
        int d = edst[e];
        if (GM && d >= NLOCAL) d = gmap[d - NLOCAL];
        dst_s[tid] = d;
    }
    __syncthreads();

    // main staging: 64 rows x 48 short8 chunks, 6/thread
    #pragma unroll
    for (int j = 0; j < 6; j++){
        int idx = j*512 + tid;
        int m   = idx/48;
        int k8  = idx - m*48;
        short8 h;
        if (k8 < 16){
            h = *(const short8*)(Ah + (size_t)src_s[m]*UNITS + k8*8);
        } else if (k8 < 32){
            h = *(const short8*)(Ah + (size_t)dst_s[m]*UNITS + (k8-16)*8);
        } else if (ENC){
            short8 z = {0,0,0,0,0,0,0,0};
            h = z;
        } else {
            int e = min(e0 + m, NEDGE-1);
            h = *(const short8*)(Eh + (size_t)e*UNITS + (k8-32)*8);
        }
        *(short8*)&feat_s[m*FSTR + k8*8] = h;
    }
    // aux staging: thread m builds its edge's [rbf(10) | tb(9) | 0..] row;
    // tb from triples CSR (avg ~0.2 entries/edge)
    if (tid < MEDGE){
        int e = min(e0 + tid, NEDGE-1);
        float tb[SBF];
        #pragma unroll
        for (int s = 0; s < SBF; s++) tb[s] = 0.0f;
        int beg = toff[e], end = toff[e+1];
        for (int t = beg; t < end; t++){
            const float* cf = t_cf + (size_t)t*SBF;
            const float* am = amlp + (size_t)t_ka[t]*SBF;
            #pragma unroll
            for (int s = 0; s < SBF; s++) tb[s] = fmaf(cf[s], am[s], tb[s]);
        }
        ushort row[32];
        #pragma unroll
        for (int k = 0; k < 10; k++) row[k] = f2bf(rbf0[(size_t)e*NRBF + k]);
        #pragma unroll
        for (int s = 0; s < SBF; s++) row[10+s] = f2bf(tb[s]);
        #pragma unroll
        for (int k = 19; k < 32; k++) row[k] = 0;
        #pragma unroll
        for (int j8 = 0; j8 < 4; j8++)
            *(short8*)&feat_s[tid*FSTR + 384 + j8*8] = *(const short8*)&row[j8*8];
    }
    __syncthreads();

    const int lane = tid & 63;
    const int w    = tid >> 6;
    const int quad = lane >> 4;
    const int l15  = lane & 15;
    const int c    = w*16 + l15;

    // ---------------- Phase 1: ge GEMM (kb0..12) + te/le (+enc) aux ----------------
    f32x4 acc_em[4], acc_eg[4], acc_te[4], acc_le[4], acc_en[ENC ? 4 : 1];
    {
        float bm = btm[c], bg = btg[c], tb = tbb[c], le = eleb[c];
        #pragma unroll
        for (int mt = 0; mt < 4; mt++){
            acc_em[mt] = splat4(bm); acc_eg[mt] = splat4(bg);
            acc_te[mt] = splat4(tb); acc_le[mt] = splat4(le);
        }
        if (ENC){
            float eb = encb[c];
            #pragma unroll
            for (int mt = 0; mt < 4; mt++) acc_en[mt] = splat4(eb);
        }
    }
    const ushort* abase = feat_s + l15*FSTR + quad*8;

    for (int ks = 0; ks < 12; ks++){
        short8 a[4];
        #pragma unroll
        for (int mt = 0; mt < 4; mt++)
            a[mt] = *(const short8*)(abase + mt*16*FSTR + ks*32);
        size_t boff = ((size_t)(ks*8 + w)*64 + lane)*8;
        short8 b_em = *(const short8*)(Wem + boff);
        short8 b_eg = *(const short8*)(Weg + boff);
        #pragma unroll
        for (int mt = 0; mt < 4; mt++){
            acc_em[mt] = __builtin_amdgcn_mfma_f32_16x16x32_bf16(a[mt], b_em, acc_em[mt], 0, 0, 0);
            acc_eg[mt] = __builtin_amdgcn_mfma_f32_16x16x32_bf16(a[mt], b_eg, acc_eg[mt], 0, 0, 0);
        }
    }
    {   // kb12 aux fragment
        size_t bx = ((size_t)w*64 + lane)*8;
        short8 b_xm = *(const short8*)(WxM + bx);
        short8 b_xg = *(const short8*)(WxG + bx);
        short8 b_te = *(const short8*)(Bte + bx);
        short8 b_le = *(const short8*)(Ble + bx);
        #pragma unroll
        for (int mt = 0; mt < 4; mt++){
            short8 ax = *(const short8*)(abase + mt*16*FSTR + 384);
            acc_em[mt] = __builtin_amdgcn_mfma_f32_16x16x32_bf16(ax, b_xm, acc_em[mt], 0, 0, 0);
            acc_eg[mt] = __builtin_amdgcn_mfma_f32_16x16x32_bf16(ax, b_xg, acc_eg[mt], 0, 0, 0);
            acc_te[mt] = __builtin_amdgcn_mfma_f32_16x16x32_bf16(ax, b_te, acc_te[mt], 0, 0, 0);
            acc_le[mt] = __builtin_amdgcn_mfma_f32_16x16x32_bf16(ax, b_le, acc_le[mt], 0, 0, 0);
        }
        if (ENC){
            short8 b_en = *(const short8*)(Benc + bx);
            #pragma unroll
            for (int mt = 0; mt < 4; mt++){
                short8 ax = *(const short8*)(abase + mt*16*FSTR + 384);
                acc_en[mt] = __builtin_amdgcn_mfma_f32_16x16x32_bf16(ax, b_en, acc_en[mt], 0, 0, 0);
            }
        }
    }

    // ---------------- Epilogue 1: E_new = E_old + tbgate + gate*el_e ----------------
    __syncthreads();
    #pragma unroll
    for (int mt = 0; mt < 4; mt++){
        #pragma unroll
        for (int r = 0; r < 4; r++){
            int ml = mt*16 + quad*4 + r;
            int e  = e0 + ml;
            if (e >= NEDGE) continue;
            float gate = gatef(acc_em[mt][r], acc_eg[mt][r]);
            float eold = ENC ? acc_en[mt][r] : bf2f(feat_s[ml*FSTR + 256 + c]);
            float enew = eold + acc_te[mt][r] + gate*acc_le[mt][r];
            feat_s[ml*FSTR + 256 + c] = f2bf(enew);
        }
    }
    __syncthreads();

    // coalesced Eh writeback from LDS E-region (2 x 16B stores/thread)
    if (STORE){
        #pragma unroll
        for (int j = 0; j < 2; j++){
            int idx = j*512 + tid;
            int row = idx >> 4;
            int q8  = idx & 15;
            int e   = e0 + row;
            if (e < NEDGE)
                *(short8*)(Eh + (size_t)e*UNITS + q8*8)
                    = *(const short8*)&feat_s[row*FSTR + 256 + q8*8];
        }
    }

    // ---------------- Phase 2: ga GEMM (full kb0..11 on E_new) + la aux ----------------
    f32x4 acc_am[4], acc_ag[4], acc_la[4];
    {
        float bm = bam[c], bg = bag[c], lb = elab[c];
        #pragma unroll
        for (int mt = 0; mt < 4; mt++){
            acc_am[mt] = splat4(bm); acc_ag[mt] = splat4(bg); acc_la[mt] = splat4(lb);
        }
    }
    for (int ks = 0; ks < 12; ks++){
        short8 a[4];
        #pragma unroll
        for (int mt = 0; mt < 4; mt++)
            a[mt] = *(const short8*)(abase + mt*16*FSTR + ks*32);
        size_t boff = ((size_t)(ks*8 + w)*64 + lane)*8;
        short8 b_am = *(const short8*)(Wam + boff);
        short8 b_ag = *(const short8*)(Wag + boff);
        #pragma unroll
        for (int mt = 0; mt < 4; mt++){
            acc_am[mt] = __builtin_amdgcn_mfma_f32_16x16x32_bf16(a[mt], b_am, acc_am[mt], 0, 0, 0);
            acc_ag[mt] = __builtin_amdgcn_mfma_f32_16x16x32_bf16(a[mt], b_ag, acc_ag[mt], 0, 0, 0);
        }
    }
    {
        size_t bx = ((size_t)w*64 + lane)*8;
        short8 b_la = *(const short8*)(Bla + bx);
        #pragma unroll
        for (int mt = 0; mt < 4; mt++){
            short8 ax = *(const short8*)(abase + mt*16*FSTR + 384);
            acc_la[mt] = __builtin_amdgcn_mfma_f32_16x16x32_bf16(ax, b_la, acc_la[mt], 0, 0, 0);
        }
    }

    // ---------------- Epilogue 2: f32 atomics into agg[src] ----------------
    #pragma unroll
    for (int mt = 0; mt < 4; mt++){
        #pragma unroll
        for (int r = 0; r < 4; r++){
            int ml = mt*16 + quad*4 + r;
            int e  = e0 + ml;
            if (e >= NEDGE) continue;
            float gate = gatef(acc_am[mt][r], acc_ag[mt][r]);
            atomicAdd(&agg[(size_t)src_s[ml]*UNITS + c], gate*acc_la[mt][r]);
        }
    }
}

// ---------------- final readout + global sum ----------------
__global__ void k_final(const float* __restrict__ A, const float* __restrict__ W1,
                        const float* __restrict__ b1, const float* __restrict__ W2,
                        const float* __restrict__ b2, const int* __restrict__ anum,
                        const float* __restrict__ escl, const float* __restrict__ eshf,
                        float* __restrict__ out){
    __shared__ float red[256];
    const int tid  = threadIdx.x;
    const int c    = tid & 127;
    const int half = tid >> 7;
    float b1c = b1[c];
    float w2c = W2[c];
    float b2v = b2[0];
    float tpart = 0.0f;
    const int npairs = NLOCAL/2;
    for (int p = blockIdx.x; p < npairs; p += gridDim.x){
        int a = 2*p + half;
        const float* h = A + (size_t)a*UNITS;
        float acc = b1c;
        for (int k = 0; k < UNITS; k++)
            acc = fmaf(h[k], W1[k*UNITS + c], acc);
        float hid = acc/(1.0f+__expf(-acc));
        int z = anum[a];
        float sc = escl[z];
        tpart = fmaf(sc*hid, w2c, tpart);
        if (c == 0) tpart += sc*b2v + eshf[z];
    }
    red[tid] = tpart;
    __syncthreads();
    for (int s = 128; s > 0; s >>= 1){
        if (tid < s) red[tid] += red[tid + s];
        __syncthreads();
    }
    if (tid == 0) atomicAdd(out, red[0]);
}

extern "C" void kernel_launch(void* const* d_in, const int* in_sizes, int n_in,
                              void* d_out, int out_size, void* d_ws, size_t ws_size,
                              hipStream_t stream){
    const int*   anum  = (const int*)d_in[0];
    const float* pos   = (const float*)d_in[1];
    const float* cell  = (const float*)d_in[2];
    const float* pbc   = (const float*)d_in[3];
    const int*   esrc  = (const int*)d_in[4];
    const int*   edst  = (const int*)d_in[5];
    const int*   tbi   = (const int*)d_in[6];
    const int*   batch = (const int*)d_in[7];
    const int*   gmap  = (const int*)d_in[8];
    const float* embw  = (const float*)d_in[10];
    const float* encw  = (const float*)d_in[11];
    const float* encb  = (const float*)d_in[12];
    const float* tbaw  = (const float*)d_in[13];
    const float* tbab  = (const float*)d_in[14];
    const float* tbgw  = (const float*)d_in[15];
    const float* tbgb  = (const float*)d_in[16];
    const float* gewm  = (const float*)d_in[17];
    const float* gebm  = (const float*)d_in[18];
    const float* gewg  = (const float*)d_in[19];
    const float* gebg  = (const float*)d_in[20];
    const float* elew  = (const float*)d_in[21];
    const float* eleb  = (const float*)d_in[22];
    const float* gawm  = (const float*)d_in[23];
    const float* gabm  = (const float*)d_in[24];
    const float* gawg  = (const float*)d_in[25];
    const float* gabg  = (const float*)d_in[26];
    const float* elaw  = (const float*)d_in[27];
    const float* elab  = (const float*)d_in[28];
    const float* fw1   = (const float*)d_in[29];
    const float* fb1   = (const float*)d_in[30];
    const float* fw2   = (const float*)d_in[31];
    const float* fb2   = (const float*)d_in[32];
    const float* escl  = (const float*)d_in[33];
    const float* eshf  = (const float*)d_in[34];
    (void)in_sizes; (void)n_in; (void)out_size; (void)ws_size;

    float* ws     = (float*)d_ws;
    float* embedF = ws;                                   // NTOTAL*128 f32
    float* aggA   = embedF + (size_t)NTOTAL*UNITS;        // NLOCAL*128 f32
    float* aggB   = aggA   + (size_t)NLOCAL*UNITS;        // NLOCAL*128 f32
    float* evec   = aggB   + (size_t)NLOCAL*UNITS;        // NEDGE*3
    float* elen   = evec   + (size_t)NEDGE*3;             // NEDGE
    float* rbf0   = elen   + (size_t)NEDGE;               // NEDGE*10
    float* amlp   = rbf0   + (size_t)NEDGE*NRBF;          // NLOCAL*9
    float* btot   = amlp   + (size_t)NLOCAL*SBF;          // 3*2*128
    int*   hist   = (int*)(btot + 3*2*128);               // NEDGE
    int*   toff   = hist + NEDGE;                         // NEDGE+1
    int*   curs   = toff + NEDGE + 1;                     // NEDGE (+pad)
    int*   t_ka   = curs + NEDGE + 3;                     // NTRIPLE
    float* t_cf   = (float*)(t_ka + NTRIPLE);             // 9*NTRIPLE (AoS)
    ushort* edgeEh = (ushort*)(t_cf + (size_t)9*NTRIPLE); // NEDGE*128 bf16
    ushort* embedAh = edgeEh + (size_t)NEDGE*UNITS;       // NTOTAL*128 bf16
    ushort* aggAh   = embedAh + (size_t)NTOTAL*UNITS;     // NLOCAL*128 bf16
    ushort* wmain  = aggAh + (size_t)NLOCAL*UNITS;        // 3*4*49152
    ushort* wext   = wmain + (size_t)3*4*49152;           // 3*2*4096
    ushort* waux   = wext  + (size_t)3*2*4096;            // 3*3*4096
    ushort* wencb  = waux  + (size_t)3*3*4096;            // 4096

    float* out = (float*)d_out;
    hipMemsetAsync(out, 0, sizeof(float), stream);
    hipMemsetAsync(hist, 0, NEDGE*sizeof(int), stream);

    k_pack_w   <<<(3*4*12*8*64 + 255)/256, 256, 0, stream>>>(gewm, gewg, gawm, gawg, wmain);
    k_pack_ext <<<(3*2*512 + 255)/256, 256, 0, stream>>>(gewm, gewg, tbgw, encw, wext);
    k_pack_aux <<<(3*3*512 + 255)/256, 256, 0, stream>>>(elew, elaw, tbgw, waux);
    k_pack_encB<<<2, 256, 0, stream>>>(encw, wencb);
    k_pack_bias<<<(3*2*128 + 255)/256, 256, 0, stream>>>(gewm, gewg, gebm, gebg, tbgb,
                                                         encb, btot);
    k_edge_geom<<<(NEDGE+255)/256, 256, 0, stream>>>(pos, cell, pbc, esrc, edst, batch,
                                                     evec, elen, rbf0);
    k_embed<<<(NTOTAL*32+255)/256, 256, 0, stream>>>(anum, embw, embedF, embedAh);
    // triples CSR: hist -> scan -> scatter (one-time, layer-independent)
    k_triple_hist   <<<(NTRIPLE+255)/256, 256, 0, stream>>>(elen, tbi, hist);
    k_scan          <<<1, 256, 0, stream>>>(hist, toff, curs);
    k_triple_scatter<<<(NTRIPLE+255)/256, 256, 0, stream>>>(evec, elen, esrc, tbi,
                                                            curs, t_ka, t_cf);

    const int gemm_blocks = (NEDGE + MEDGE - 1)/MEDGE;
    float*  Fin[3]  = { embedF, aggA, aggB };
    float*  Aout[3] = { aggA,   aggB, aggA };
    for (int L = 0; L < NLAYERS; L++){
        const ushort* wmL = wmain + (size_t)L*4*49152;
        const ushort* wxL = wext  + (size_t)L*2*4096;
        const ushort* waL = waux  + (size_t)L*3*4096;
        k_tb_mlp<<<(NLOCAL+255)/256, 256, 0, stream>>>(Fin[L],
            tbaw + (size_t)L*UNITS*SBF, tbab + (size_t)L*SBF, amlp, Aout[L], aggAh);
        const ushort* AhL = (L == 0) ? embedAh : aggAh;
        #define GATED_ARGS AhL, gmap, edgeEh, esrc, edst, rbf0, toff, t_ka, t_cf, amlp, \
            wmL + 0*49152, wmL + 1*49152, wmL + 2*49152, wmL + 3*49152, \
            wxL + 0*4096,  wxL + 1*4096, \
            waL + 0*4096,  waL + 1*4096, waL + 2*4096, wencb, \
            btot + (size_t)L*2*128, btot + (size_t)L*2*128 + 128, \
            gabm + (size_t)L*UNITS, gabg + (size_t)L*UNITS, \
            tbgb + (size_t)L*UNITS, eleb + (size_t)L*UNITS, elab + (size_t)L*UNITS, \
            encb, Aout[L]
        if (L == 0)
            k_gated_fused<1,0,1><<<gemm_blocks, 512, 0, stream>>>(GATED_ARGS);
        else if (L == 1)
            k_gated_fused<0,1,1><<<gemm_blocks, 512, 0, stream>>>(GATED_ARGS);
        else
            k_gated_fused<0,1,0><<<gemm_blocks, 512, 0, stream>>>(GATED_ARGS);
        #undef GATED_ARGS
    }
    k_final<<<1024, 256, 0, stream>>>(aggA, fw1, fb1, fw2, fb2, anum, escl, eshf, out);
}

// Round 16
// 1235.418 us; speedup vs baseline: 1.4301x; 1.4301x over previous
//
#include <hip/hip_runtime.h>
#include <math.h>

#define UNITS   128
#define NRBF    10
#define SBF     9
#define NLAYERS 3
#define NELEM   95
#define NTOTAL  60000
#define NLOCAL  50000
#define NGHOST  10000
#define NEDGE   250000
#define NTRIPLE 1000000
#define CUTOFF  5.0f
#define TBCUT   4.0f
#define PI_F    3.14159265358979323846f
#define FSTR    424   // feat row stride in ushorts: 13 kb * 32 + 8 pad
#define MEDGE   64    // edges per gated block
#define SCHUNK  1024
#define NCHUNK  ((NEDGE + SCHUNK - 1)/SCHUNK)   // 245

typedef __attribute__((ext_vector_type(8))) short short8;
typedef __attribute__((ext_vector_type(4))) float f32x4;

__device__ __forceinline__ float sigm(float x){ return 1.0f/(1.0f+__expf(-x)); }
__device__ __forceinline__ float polycut(float r){
    float q = r*(1.0f/TBCUT);
    float q2 = q*q, q3 = q2*q;
    float p = 1.0f - 6.0f*q2*q3 + 15.0f*q2*q2 - 10.0f*q3;
    return (r <= TBCUT) ? p : 0.0f;
}
__device__ __forceinline__ ushort f2bf(float x){
    unsigned u = __float_as_uint(x);
    unsigned r = (u + 0x7fffu + ((u>>16)&1u)) >> 16;
    return (ushort)r;
}
__device__ __forceinline__ float bf2f(ushort h){
    return __uint_as_float(((unsigned)h) << 16);
}
__device__ __forceinline__ f32x4 splat4(float x){ f32x4 v = {x,x,x,x}; return v; }
__device__ __forceinline__ float gatef(float xm, float xg){
    float d = (1.0f+__expf(-xm))*(1.0f+__expf(-xg));
    return xm*__builtin_amdgcn_rcpf(d);
}

// ---------------- edge geometry + rbf ----------------
__global__ void k_edge_geom(const float* __restrict__ pos, const float* __restrict__ cell,
                            const float* __restrict__ pbc, const int* __restrict__ src,
                            const int* __restrict__ dst, const int* __restrict__ batch,
                            float* __restrict__ evec, float* __restrict__ elen,
                            float* __restrict__ rbf0){
    int e = blockIdx.x*blockDim.x + threadIdx.x;
    if (e >= NEDGE) return;
    int s = src[e], d = dst[e];
    int b = batch[s];
    const float* C = cell + b*9;
    float p0 = pbc[e*3+0], p1 = pbc[e*3+1], p2 = pbc[e*3+2];
    float vx = pos[s*3+0] - (pos[d*3+0] + p0*C[0] + p1*C[3] + p2*C[6]);
    float vy = pos[s*3+1] - (pos[d*3+1] + p0*C[1] + p1*C[4] + p2*C[7]);
    float vz = pos[s*3+2] - (pos[d*3+2] + p0*C[2] + p1*C[5] + p2*C[8]);
    float r = sqrtf(vx*vx + vy*vy + vz*vz);
    evec[e*3+0] = vx; evec[e*3+1] = vy; evec[e*3+2] = vz;
    elen[e] = r;
    #pragma unroll
    for (int i = 0; i < NRBF; i++){
        float mu = (CUTOFF/(NRBF-1))*i;
        float dm = r - mu;
        rbf0[e*NRBF + i] = __expf(-dm*dm*2.0f);
    }
}

// ---------------- atom embedding gather (f32 + NTOTAL bf16 mirror) ----------------
__global__ void k_embed(const int* __restrict__ anum, const float* __restrict__ embw,
                        float* __restrict__ A, ushort* __restrict__ Ah){
    int t = blockIdx.x*blockDim.x + threadIdx.x;
    if (t >= NTOTAL*32) return;
    int a = t >> 5, q = t & 31;
    float4 v = ((const float4*)embw)[anum[a]*32 + q];
    ((float4*)A)[t] = v;
    ushort4 h;
    h.x = f2bf(v.x); h.y = f2bf(v.y); h.z = f2bf(v.z); h.w = f2bf(v.w);
    ((ushort4*)Ah)[t] = h;
}

// ---------------- pack main gated-MLP weights: [L][mat:4][kb:12][nt:8][lane:64][j:8] ----------------
__global__ void k_pack_w(const float* __restrict__ gewm, const float* __restrict__ gewg,
                         const float* __restrict__ gawm, const float* __restrict__ gawg,
                         ushort* __restrict__ wp){
    int t = blockIdx.x*blockDim.x + threadIdx.x;
    if (t >= 3*4*12*8*64) return;
    int lane = t & 63;
    int nt   = (t>>6) & 7;
    int rest = t >> 9;
    int kb   = rest % 12;
    int r2   = rest / 12;
    int mat  = r2 & 3;
    int L    = r2 >> 2;
    const float* src;
    if      (mat == 0) src = gewm;
    else if (mat == 1) src = gewg;
    else if (mat == 2) src = gawm;
    else               src = gawg;
    src += (size_t)L*384*128;
    int n = nt*16 + (lane & 15);
    int kbase = kb*32 + (lane>>4)*8;
    ushort* dst = wp + (size_t)t*8;
    #pragma unroll
    for (int j = 0; j < 8; j++) dst[j] = f2bf(src[(size_t)(kbase+j)*128 + n]);
}

// ---------------- pack kb12 ext weights ----------------
__global__ void k_pack_ext(const float* __restrict__ gewm, const float* __restrict__ gewg,
                           const float* __restrict__ tbg, const float* __restrict__ encw,
                           ushort* __restrict__ wext){
    int t = blockIdx.x*blockDim.x + threadIdx.x;
    if (t >= 3*2*512) return;
    int lane = t & 63;
    int nt   = (t>>6) & 7;
    int mat  = (t>>9) & 1;
    int L    = t >> 10;
    const float* W  = ((mat==0)? gewm : gewg) + (size_t)L*384*128;
    const float* tg = tbg + (size_t)L*SBF*UNITS;
    int n = nt*16 + (lane & 15);
    ushort* dst = wext + (size_t)t*8;
    #pragma unroll
    for (int j = 0; j < 8; j++){
        int k = (lane>>4)*8 + j;
        float v = 0.0f;
        if (k >= 10 && k <= 18){
            int s = k - 10;
            for (int kk = 0; kk < 128; kk++)
                v = fmaf(tg[s*UNITS+kk], W[(size_t)(256+kk)*128 + n], v);
        } else if (k < 10 && L == 0){
            for (int kk = 0; kk < 128; kk++)
                v = fmaf(encw[k*UNITS+kk], W[(size_t)(256+kk)*128 + n], v);
        }
        dst[j] = f2bf(v);
    }
}

// ---------------- pack aux B mats: el_e, el_a, tbgate ----------------
__global__ void k_pack_aux(const float* __restrict__ elew, const float* __restrict__ elaw,
                           const float* __restrict__ tbg, ushort* __restrict__ waux){
    int t = blockIdx.x*blockDim.x + threadIdx.x;
    if (t >= 3*3*512) return;
    int lane = t & 63;
    int nt   = (t>>6) & 7;
    int rest = t >> 9;
    int mat  = rest % 3;
    int L    = rest / 3;
    int n = nt*16 + (lane & 15);
    ushort* dst = waux + (size_t)t*8;
    #pragma unroll
    for (int j = 0; j < 8; j++){
        int k = (lane>>4)*8 + j;
        float v = 0.0f;
        if (mat == 0){ if (k < 10) v = elew[(size_t)L*NRBF*UNITS + k*UNITS + n]; }
        else if (mat == 1){ if (k < 10) v = elaw[(size_t)L*NRBF*UNITS + k*UNITS + n]; }
        else { if (k >= 10 && k <= 18) v = tbg[(size_t)L*SBF*UNITS + (k-10)*UNITS + n]; }
        dst[j] = f2bf(v);
    }
}

// ---------------- pack enc B mat (E0 via MFMA, L0 only) ----------------
__global__ void k_pack_encB(const float* __restrict__ encw, ushort* __restrict__ wencb){
    int t = blockIdx.x*blockDim.x + threadIdx.x;
    if (t >= 512) return;
    int lane = t & 63;
    int nt   = t >> 6;
    int n = nt*16 + (lane & 15);
    ushort* dst = wencb + (size_t)t*8;
    #pragma unroll
    for (int j = 0; j < 8; j++){
        int k = (lane>>4)*8 + j;
        float v = (k < 10) ? encw[k*UNITS + n] : 0.0f;
        dst[j] = f2bf(v);
    }
}

// ---------------- bias totals ----------------
__global__ void k_pack_bias(const float* __restrict__ gewm, const float* __restrict__ gewg,
                            const float* __restrict__ gebm, const float* __restrict__ gebg,
                            const float* __restrict__ tbb, const float* __restrict__ encb,
                            float* __restrict__ btot){
    int t = blockIdx.x*blockDim.x + threadIdx.x;
    if (t >= 3*2*128) return;
    int n = t & 127;
    int mat = (t>>7) & 1;
    int L = t >> 8;
    const float* W = ((mat==0)? gewm : gewg) + (size_t)L*384*128;
    const float* be = ((mat==0)? gebm : gebg) + (size_t)L*UNITS;
    const float* tb = tbb + (size_t)L*UNITS;
    float v = be[n];
    for (int kk = 0; kk < 128; kk++){
        float f = tb[kk];
        if (L == 0) f += encb[kk];
        v = fmaf(f, W[(size_t)(256+kk)*128 + n], v);
    }
    btot[t] = v;
}

// ---------------- per-layer: atom sbf mlp + seed aggOut + bf16 mirror ----------------
__global__ void k_tb_mlp(const float* __restrict__ Fin, const float* __restrict__ W,
                         const float* __restrict__ b, float* __restrict__ out,
                         float* __restrict__ aggOut, ushort* __restrict__ Ah){
    int a = blockIdx.x*blockDim.x + threadIdx.x;
    if (a >= NLOCAL) return;
    float acc[SBF];
    #pragma unroll
    for (int s = 0; s < SBF; s++) acc[s] = b[s];
    const float4* row4 = (const float4*)(Fin + (size_t)a*UNITS);
    float4* agg4 = (float4*)(aggOut + (size_t)a*UNITS);
    ushort4* ah4 = (ushort4*)(Ah + (size_t)a*UNITS);
    for (int k4 = 0; k4 < 32; k4++){
        float4 v = row4[k4];
        agg4[k4] = v;
        ushort4 h;
        h.x = f2bf(v.x); h.y = f2bf(v.y); h.z = f2bf(v.z); h.w = f2bf(v.w);
        ah4[k4] = h;
        const float* w = W + (k4*4)*SBF;
        #pragma unroll
        for (int s = 0; s < SBF; s++){
            acc[s] = fmaf(v.x, w[s],        acc[s]);
            acc[s] = fmaf(v.y, w[s+SBF],    acc[s]);
            acc[s] = fmaf(v.z, w[s+2*SBF],  acc[s]);
            acc[s] = fmaf(v.w, w[s+3*SBF],  acc[s]);
        }
    }
    #pragma unroll
    for (int s = 0; s < SBF; s++) out[a*SBF + s] = sigm(acc[s]);
}

// ---------------- triples CSR build (one-time, layer-independent) ----------------
__global__ void k_triple_hist(const float* __restrict__ elen, const int* __restrict__ tbi,
                              int* __restrict__ hist){
    int t = blockIdx.x*blockDim.x + threadIdx.x;
    if (t >= NTRIPLE) return;
    int ij = tbi[2*t], ik = tbi[2*t+1];
    if (polycut(elen[ij])*polycut(elen[ik]) != 0.0f)
        atomicAdd(&hist[ij], 1);
}
// 3-phase parallel scan (R15's 1-block serial scan was 589us: latency-serialized)
// A: per-1024-chunk LDS scan -> local exclusive prefix in toff, chunk total in bsum
__global__ void k_scanA(const int* __restrict__ hist, int* __restrict__ toff,
                        int* __restrict__ bsum){
    __shared__ int sh[256];
    int b = blockIdx.x, tid = threadIdx.x;
    int base = b*SCHUNK + tid*4;
    int v0 = 0, v1 = 0, v2 = 0, v3 = 0;
    if (base+0 < NEDGE) v0 = hist[base+0];
    if (base+1 < NEDGE) v1 = hist[base+1];
    if (base+2 < NEDGE) v2 = hist[base+2];
    if (base+3 < NEDGE) v3 = hist[base+3];
    int tsum = v0+v1+v2+v3;
    sh[tid] = tsum;
    __syncthreads();
    for (int off = 1; off < 256; off <<= 1){
        int x = (tid >= off) ? sh[tid-off] : 0;
        __syncthreads();
        sh[tid] += x;
        __syncthreads();
    }
    int run = (tid == 0) ? 0 : sh[tid-1];
    if (tid == 255) bsum[b] = sh[255];
    if (base+0 < NEDGE) toff[base+0] = run; run += v0;
    if (base+1 < NEDGE) toff[base+1] = run; run += v1;
    if (base+2 < NEDGE) toff[base+2] = run; run += v2;
    if (base+3 < NEDGE) toff[base+3] = run;
}
// B: scan the NCHUNK chunk totals (single tiny block)
__global__ void k_scanB(int* __restrict__ bsum, int* __restrict__ total){
    __shared__ int sh[256];
    int tid = threadIdx.x;
    int v = (tid < NCHUNK) ? bsum[tid] : 0;
    sh[tid] = v;
    __syncthreads();
    for (int off = 1; off < 256; off <<= 1){
        int x = (tid >= off) ? sh[tid-off] : 0;
        __syncthreads();
        sh[tid] += x;
        __syncthreads();
    }
    if (tid < NCHUNK) bsum[tid] = sh[tid] - v;   // exclusive
    if (tid == 255) *total = sh[255];
}
// C: add chunk base, copy cursor, set toff[NEDGE]
__global__ void k_scanC(int* __restrict__ toff, int* __restrict__ curs,
                        const int* __restrict__ bsum, const int* __restrict__ total){
    int i = blockIdx.x*blockDim.x + threadIdx.x;
    if (i < NEDGE){
        int v = toff[i] + bsum[i/SCHUNK];
        toff[i] = v;
        curs[i] = v;
    }
    if (i == 0) toff[NEDGE] = *total;
}
// pass 2: full geometry, scatter into CSR slots
__global__ void k_triple_scatter(const float* __restrict__ evec, const float* __restrict__ elen,
                                 const int* __restrict__ esrc, const int* __restrict__ tbi,
                                 int* __restrict__ curs, int* __restrict__ t_ka,
                                 float* __restrict__ t_cf){
    int t = blockIdx.x*blockDim.x + threadIdx.x;
    if (t >= NTRIPLE) return;
    int ij = tbi[2*t], ik = tbi[2*t+1];
    float rij = elen[ij], rik = elen[ik];
    float cc = polycut(rij)*polycut(rik);
    if (cc == 0.0f) return;
    float ax = evec[ij*3+0], ay = evec[ij*3+1], az = evec[ij*3+2];
    float bx = evec[ik*3+0], by = evec[ik*3+1], bz = evec[ik*3+2];
    float dot = ax*bx + ay*by + az*bz;
    float c = dot/(rij*rik + 1e-12f);
    c = fminf(fmaxf(c, -1.0f + 1e-7f), 1.0f - 1e-7f);
    float a0 = 1.0f, a1 = c, a2 = 2.0f*c*c - 1.0f;
    float x = rik*(PI_F/TBCUT);
    float s1, c1;
    __sincosf(x, &s1, &c1);
    float s2 = 2.0f*s1*c1;
    float s3 = s1*(3.0f - 4.0f*s1*s1);
    float inv = 1.0f/(rik + 1e-6f);
    float r0 = s1*inv, r1 = s2*inv, r2 = s3*inv;
    int pos = atomicAdd(&curs[ij], 1);
    t_ka[pos] = esrc[ik];
    float* d = t_cf + (size_t)pos*SBF;
    d[0] = r0*a0*cc; d[1] = r0*a1*cc; d[2] = r0*a2*cc;
    d[3] = r1*a0*cc; d[4] = r1*a1*cc; d[5] = r1*a2*cc;
    d[6] = r2*a0*cc; d[7] = r2*a1*cc; d[8] = r2*a2*cc;
}

// ---------------- fused per-layer gated blocks (ge + ga), all-MFMA ----------------
// R12-proven config: 64 edges/block, 512 threads, src_s/dst_s index cache in LDS.
// ENC/GM/STORE compile-time. tb(9) per edge computed INLINE from triples CSR
// (avg ~0.2 triples/edge). Coalesced Eh writeback. NO launch_bounds (R5/R7).
template<int ENC, int GM, int STORE>
__global__
void k_gated_fused(const ushort* __restrict__ Ah, const int* __restrict__ gmap,
                   ushort* __restrict__ Eh,
                   const int* __restrict__ esrc, const int* __restrict__ edst,
                   const float* __restrict__ rbf0,
                   const int* __restrict__ toff, const int* __restrict__ t_ka,
                   const float* __restrict__ t_cf, const float* __restrict__ amlp,
                   const ushort* __restrict__ Wem, const ushort* __restrict__ Weg,
                   const ushort* __restrict__ Wam, const ushort* __restrict__ Wag,
                   const ushort* __restrict__ WxM, const ushort* __restrict__ WxG,
                   const ushort* __restrict__ Ble, const ushort* __restrict__ Bla,
                   const ushort* __restrict__ Bte, const ushort* __restrict__ Benc,
                   const float* __restrict__ btm, const float* __restrict__ btg,
                   const float* __restrict__ bam, const float* __restrict__ bag,
                   const float* __restrict__ tbb, const float* __restrict__ eleb,
                   const float* __restrict__ elab, const float* __restrict__ encb,
                   float* __restrict__ agg){
    __shared__ __align__(16) ushort feat_s[MEDGE*FSTR];
    __shared__ int src_s[MEDGE];
    __shared__ int dst_s[MEDGE];

    const int tid = threadIdx.x;
    const int e0  = blockIdx.x*MEDGE;

    if (tid < MEDGE){
        int e = min(e0 + tid, NEDGE-1);
        src_s[tid] = esrc[e];
        int d = edst[e];
        if (GM && d >= NLOCAL) d = gmap[d - NLOCAL];
        dst_s[tid] = d;
    }
    __syncthreads();

    // main staging: 64 rows x 48 short8 chunks, 6/thread
    #pragma unroll
    for (int j = 0; j < 6; j++){
        int idx = j*512 + tid;
        int m   = idx/48;
        int k8  = idx - m*48;
        short8 h;
        if (k8 < 16){
            h = *(const short8*)(Ah + (size_t)src_s[m]*UNITS + k8*8);
        } else if (k8 < 32){
            h = *(const short8*)(Ah + (size_t)dst_s[m]*UNITS + (k8-16)*8);
        } else if (ENC){
            short8 z = {0,0,0,0,0,0,0,0};
            h = z;
        } else {
            int e = min(e0 + m, NEDGE-1);
            h = *(const short8*)(Eh + (size_t)e*UNITS + (k8-32)*8);
        }
        *(short8*)&feat_s[m*FSTR + k8*8] = h;
    }
    // aux staging: thread m builds its edge's [rbf(10) | tb(9) | 0..] row
    if (tid < MEDGE){
        int e = min(e0 + tid, NEDGE-1);
        float tb[SBF];
        #pragma unroll
        for (int s = 0; s < SBF; s++) tb[s] = 0.0f;
        int beg = toff[e], end = toff[e+1];
        for (int t = beg; t < end; t++){
            const float* cf = t_cf + (size_t)t*SBF;
            const float* am = amlp + (size_t)t_ka[t]*SBF;
            #pragma unroll
            for (int s = 0; s < SBF; s++) tb[s] = fmaf(cf[s], am[s], tb[s]);
        }
        ushort row[32];
        #pragma unroll
        for (int k = 0; k < 10; k++) row[k] = f2bf(rbf0[(size_t)e*NRBF + k]);
        #pragma unroll
        for (int s = 0; s < SBF; s++) row[10+s] = f2bf(tb[s]);
        #pragma unroll
        for (int k = 19; k < 32; k++) row[k] = 0;
        #pragma unroll
        for (int j8 = 0; j8 < 4; j8++)
            *(short8*)&feat_s[tid*FSTR + 384 + j8*8] = *(const short8*)&row[j8*8];
    }
    __syncthreads();

    const int lane = tid & 63;
    const int w    = tid >> 6;
    const int quad = lane >> 4;
    const int l15  = lane & 15;
    const int c    = w*16 + l15;

    // ---------------- Phase 1: ge GEMM (kb0..12) + te/le (+enc) aux ----------------
    f32x4 acc_em[4], acc_eg[4], acc_te[4], acc_le[4], acc_en[ENC ? 4 : 1];
    {
        float bm = btm[c], bg = btg[c], tb = tbb[c], le = eleb[c];
        #pragma unroll
        for (int mt = 0; mt < 4; mt++){
            acc_em[mt] = splat4(bm); acc_eg[mt] = splat4(bg);
            acc_te[mt] = splat4(tb); acc_le[mt] = splat4(le);
        }
        if (ENC){
            float eb = encb[c];
            #pragma unroll
            for (int mt = 0; mt < 4; mt++) acc_en[mt] = splat4(eb);
        }
    }
    const ushort* abase = feat_s + l15*FSTR + quad*8;

    for (int ks = 0; ks < 12; ks++){
        short8 a[4];
        #pragma unroll
        for (int mt = 0; mt < 4; mt++)
            a[mt] = *(const short8*)(abase + mt*16*FSTR + ks*32);
        size_t boff = ((size_t)(ks*8 + w)*64 + lane)*8;
        short8 b_em = *(const short8*)(Wem + boff);
        short8 b_eg = *(const short8*)(Weg + boff);
        #pragma unroll
        for (int mt = 0; mt < 4; mt++){
            acc_em[mt] = __builtin_amdgcn_mfma_f32_16x16x32_bf16(a[mt], b_em, acc_em[mt], 0, 0, 0);
            acc_eg[mt] = __builtin_amdgcn_mfma_f32_16x16x32_bf16(a[mt], b_eg, acc_eg[mt], 0, 0, 0);
        }
    }
    {   // kb12 aux fragment
        size_t bx = ((size_t)w*64 + lane)*8;
        short8 b_xm = *(const short8*)(WxM + bx);
        short8 b_xg = *(const short8*)(WxG + bx);
        short8 b_te = *(const short8*)(Bte + bx);
        short8 b_le = *(const short8*)(Ble + bx);
        #pragma unroll
        for (int mt = 0; mt < 4; mt++){
            short8 ax = *(const short8*)(abase + mt*16*FSTR + 384);
            acc_em[mt] = __builtin_amdgcn_mfma_f32_16x16x32_bf16(ax, b_xm, acc_em[mt], 0, 0, 0);
            acc_eg[mt] = __builtin_amdgcn_mfma_f32_16x16x32_bf16(ax, b_xg, acc_eg[mt], 0, 0, 0);
            acc_te[mt] = __builtin_amdgcn_mfma_f32_16x16x32_bf16(ax, b_te, acc_te[mt], 0, 0, 0);
            acc_le[mt] = __builtin_amdgcn_mfma_f32_16x16x32_bf16(ax, b_le, acc_le[mt], 0, 0, 0);
        }
        if (ENC){
            short8 b_en = *(const short8*)(Benc + bx);
            #pragma unroll
            for (int mt = 0; mt < 4; mt++){
                short8 ax = *(const short8*)(abase + mt*16*FSTR + 384);
                acc_en[mt] = __builtin_amdgcn_mfma_f32_16x16x32_bf16(ax, b_en, acc_en[mt], 0, 0, 0);
            }
        }
    }

    // ---------------- Epilogue 1: E_new = E_old + tbgate + gate*el_e ----------------
    __syncthreads();
    #pragma unroll
    for (int mt = 0; mt < 4; mt++){
        #pragma unroll
        for (int r = 0; r < 4; r++){
            int ml = mt*16 + quad*4 + r;
            int e  = e0 + ml;
            if (e >= NEDGE) continue;
            float gate = gatef(acc_em[mt][r], acc_eg[mt][r]);
            float eold = ENC ? acc_en[mt][r] : bf2f(feat_s[ml*FSTR + 256 + c]);
            float enew = eold + acc_te[mt][r] + gate*acc_le[mt][r];
            feat_s[ml*FSTR + 256 + c] = f2bf(enew);
        }
    }
    __syncthreads();

    // coalesced Eh writeback from LDS E-region (2 x 16B stores/thread)
    if (STORE){
        #pragma unroll
        for (int j = 0; j < 2; j++){
            int idx = j*512 + tid;
            int row = idx >> 4;
            int q8  = idx & 15;
            int e   = e0 + row;
            if (e < NEDGE)
                *(short8*)(Eh + (size_t)e*UNITS + q8*8)
                    = *(const short8*)&feat_s[row*FSTR + 256 + q8*8];
        }
    }

    // ---------------- Phase 2: ga GEMM (full kb0..11 on E_new) + la aux ----------------
    f32x4 acc_am[4], acc_ag[4], acc_la[4];
    {
        float bm = bam[c], bg = bag[c], lb = elab[c];
        #pragma unroll
        for (int mt = 0; mt < 4; mt++){
            acc_am[mt] = splat4(bm); acc_ag[mt] = splat4(bg); acc_la[mt] = splat4(lb);
        }
    }
    for (int ks = 0; ks < 12; ks++){
        short8 a[4];
        #pragma unroll
        for (int mt = 0; mt < 4; mt++)
            a[mt] = *(const short8*)(abase + mt*16*FSTR + ks*32);
        size_t boff = ((size_t)(ks*8 + w)*64 + lane)*8;
        short8 b_am = *(const short8*)(Wam + boff);
        short8 b_ag = *(const short8*)(Wag + boff);
        #pragma unroll
        for (int mt = 0; mt < 4; mt++){
            acc_am[mt] = __builtin_amdgcn_mfma_f32_16x16x32_bf16(a[mt], b_am, acc_am[mt], 0, 0, 0);
            acc_ag[mt] = __builtin_amdgcn_mfma_f32_16x16x32_bf16(a[mt], b_ag, acc_ag[mt], 0, 0, 0);
        }
    }
    {
        size_t bx = ((size_t)w*64 + lane)*8;
        short8 b_la = *(const short8*)(Bla + bx);
        #pragma unroll
        for (int mt = 0; mt < 4; mt++){
            short8 ax = *(const short8*)(abase + mt*16*FSTR + 384);
            acc_la[mt] = __builtin_amdgcn_mfma_f32_16x16x32_bf16(ax, b_la, acc_la[mt], 0, 0, 0);
        }
    }

    // ---------------- Epilogue 2: f32 atomics into agg[src] ----------------
    #pragma unroll
    for (int mt = 0; mt < 4; mt++){
        #pragma unroll
        for (int r = 0; r < 4; r++){
            int ml = mt*16 + quad*4 + r;
            int e  = e0 + ml;
            if (e >= NEDGE) continue;
            float gate = gatef(acc_am[mt][r], acc_ag[mt][r]);
            atomicAdd(&agg[(size_t)src_s[ml]*UNITS + c], gate*acc_la[mt][r]);
        }
    }
}

// ---------------- final readout + global sum ----------------
__global__ void k_final(const float* __restrict__ A, const float* __restrict__ W1,
                        const float* __restrict__ b1, const float* __restrict__ W2,
                        const float* __restrict__ b2, const int* __restrict__ anum,
                        const float* __restrict__ escl, const float* __restrict__ eshf,
                        float* __restrict__ out){
    __shared__ float red[256];
    const int tid  = threadIdx.x;
    const int c    = tid & 127;
    const int half = tid >> 7;
    float b1c = b1[c];
    float w2c = W2[c];
    float b2v = b2[0];
    float tpart = 0.0f;
    const int npairs = NLOCAL/2;
    for (int p = blockIdx.x; p < npairs; p += gridDim.x){
        int a = 2*p + half;
        const float* h = A + (size_t)a*UNITS;
        float acc = b1c;
        for (int k = 0; k < UNITS; k++)
            acc = fmaf(h[k], W1[k*UNITS + c], acc);
        float hid = acc/(1.0f+__expf(-acc));
        int z = anum[a];
        float sc = escl[z];
        tpart = fmaf(sc*hid, w2c, tpart);
        if (c == 0) tpart += sc*b2v + eshf[z];
    }
    red[tid] = tpart;
    __syncthreads();
    for (int s = 128; s > 0; s >>= 1){
        if (tid < s) red[tid] += red[tid + s];
        __syncthreads();
    }
    if (tid == 0) atomicAdd(out, red[0]);
}

extern "C" void kernel_launch(void* const* d_in, const int* in_sizes, int n_in,
                              void* d_out, int out_size, void* d_ws, size_t ws_size,
                              hipStream_t stream){
    const int*   anum  = (const int*)d_in[0];
    const float* pos   = (const float*)d_in[1];
    const float* cell  = (const float*)d_in[2];
    const float* pbc   = (const float*)d_in[3];
    const int*   esrc  = (const int*)d_in[4];
    const int*   edst  = (const int*)d_in[5];
    const int*   tbi   = (const int*)d_in[6];
    const int*   batch = (const int*)d_in[7];
    const int*   gmap  = (const int*)d_in[8];
    const float* embw  = (const float*)d_in[10];
    const float* encw  = (const float*)d_in[11];
    const float* encb  = (const float*)d_in[12];
    const float* tbaw  = (const float*)d_in[13];
    const float* tbab  = (const float*)d_in[14];
    const float* tbgw  = (const float*)d_in[15];
    const float* tbgb  = (const float*)d_in[16];
    const float* gewm  = (const float*)d_in[17];
    const float* gebm  = (const float*)d_in[18];
    const float* gewg  = (const float*)d_in[19];
    const float* gebg  = (const float*)d_in[20];
    const float* elew  = (const float*)d_in[21];
    const float* eleb  = (const float*)d_in[22];
    const float* gawm  = (const float*)d_in[23];
    const float* gabm  = (const float*)d_in[24];
    const float* gawg  = (const float*)d_in[25];
    const float* gabg  = (const float*)d_in[26];
    const float* elaw  = (const float*)d_in[27];
    const float* elab  = (const float*)d_in[28];
    const float* fw1   = (const float*)d_in[29];
    const float* fb1   = (const float*)d_in[30];
    const float* fw2   = (const float*)d_in[31];
    const float* fb2   = (const float*)d_in[32];
    const float* escl  = (const float*)d_in[33];
    const float* eshf  = (const float*)d_in[34];
    (void)in_sizes; (void)n_in; (void)out_size; (void)ws_size;

    float* ws     = (float*)d_ws;
    float* embedF = ws;                                   // NTOTAL*128 f32
    float* aggA   = embedF + (size_t)NTOTAL*UNITS;        // NLOCAL*128 f32
    float* aggB   = aggA   + (size_t)NLOCAL*UNITS;        // NLOCAL*128 f32
    float* evec   = aggB   + (size_t)NLOCAL*UNITS;        // NEDGE*3
    float* elen   = evec   + (size_t)NEDGE*3;             // NEDGE
    float* rbf0   = elen   + (size_t)NEDGE;               // NEDGE*10
    float* amlp   = rbf0   + (size_t)NEDGE*NRBF;          // NLOCAL*9
    float* btot   = amlp   + (size_t)NLOCAL*SBF;          // 3*2*128
    int*   hist   = (int*)(btot + 3*2*128);               // NEDGE
    int*   toff   = hist + NEDGE;                         // NEDGE+1
    int*   curs   = toff + NEDGE + 1;                     // NEDGE (+pad)
    int*   bsum   = curs + NEDGE + 3;                     // NCHUNK (+pad)
    int*   total  = bsum + NCHUNK + 1;                    // 1 (+pad)
    int*   t_ka   = total + 4;                            // NTRIPLE
    float* t_cf   = (float*)(t_ka + NTRIPLE);             // 9*NTRIPLE (AoS)
    ushort* edgeEh = (ushort*)(t_cf + (size_t)9*NTRIPLE); // NEDGE*128 bf16
    ushort* embedAh = edgeEh + (size_t)NEDGE*UNITS;       // NTOTAL*128 bf16
    ushort* aggAh   = embedAh + (size_t)NTOTAL*UNITS;     // NLOCAL*128 bf16
    ushort* wmain  = aggAh + (size_t)NLOCAL*UNITS;        // 3*4*49152
    ushort* wext   = wmain + (size_t)3*4*49152;           // 3*2*4096
    ushort* waux   = wext  + (size_t)3*2*4096;            // 3*3*4096
    ushort* wencb  = waux  + (size_t)3*3*4096;            // 4096

    float* out = (float*)d_out;
    hipMemsetAsync(out, 0, sizeof(float), stream);
    hipMemsetAsync(hist, 0, NEDGE*sizeof(int), stream);

    k_pack_w   <<<(3*4*12*8*64 + 255)/256, 256, 0, stream>>>(gewm, gewg, gawm, gawg, wmain);
    k_pack_ext <<<(3*2*512 + 255)/256, 256, 0, stream>>>(gewm, gewg, tbgw, encw, wext);
    k_pack_aux <<<(3*3*512 + 255)/256, 256, 0, stream>>>(elew, elaw, tbgw, waux);
    k_pack_encB<<<2, 256, 0, stream>>>(encw, wencb);
    k_pack_bias<<<(3*2*128 + 255)/256, 256, 0, stream>>>(gewm, gewg, gebm, gebg, tbgb,
                                                         encb, btot);
    k_edge_geom<<<(NEDGE+255)/256, 256, 0, stream>>>(pos, cell, pbc, esrc, edst, batch,
                                                     evec, elen, rbf0);
    k_embed<<<(NTOTAL*32+255)/256, 256, 0, stream>>>(anum, embw, embedF, embedAh);
    // triples CSR: hist -> 3-phase scan -> scatter (one-time, layer-independent)
    k_triple_hist<<<(NTRIPLE+255)/256, 256, 0, stream>>>(elen, tbi, hist);
    k_scanA<<<NCHUNK, 256, 0, stream>>>(hist, toff, bsum);
    k_scanB<<<1, 256, 0, stream>>>(bsum, total);
    k_scanC<<<(NEDGE+255)/256, 256, 0, stream>>>(toff, curs, bsum, total);
    k_triple_scatter<<<(NTRIPLE+255)/256, 256, 0, stream>>>(evec, elen, esrc, tbi,
                                                            curs, t_ka, t_cf);

    const int gemm_blocks = (NEDGE + MEDGE - 1)/MEDGE;
    float*  Fin[3]  = { embedF, aggA, aggB };
    float*  Aout[3] = { aggA,   aggB, aggA };
    for (int L = 0; L < NLAYERS; L++){
        const ushort* wmL = wmain + (size_t)L*4*49152;
        const ushort* wxL = wext  + (size_t)L*2*4096;
        const ushort* waL = waux  + (size_t)L*3*4096;
        k_tb_mlp<<<(NLOCAL+255)/256, 256, 0, stream>>>(Fin[L],
            tbaw + (size_t)L*UNITS*SBF, tbab + (size_t)L*SBF, amlp, Aout[L], aggAh);
        const ushort* AhL = (L == 0) ? embedAh : aggAh;
        #define GATED_ARGS AhL, gmap, edgeEh, esrc, edst, rbf0, toff, t_ka, t_cf, amlp, \
            wmL + 0*49152, wmL + 1*49152, wmL + 2*49152, wmL + 3*49152, \
            wxL + 0*4096,  wxL + 1*4096, \
            waL + 0*4096,  waL + 1*4096, waL + 2*4096, wencb, \
            btot + (size_t)L*2*128, btot + (size_t)L*2*128 + 128, \
            gabm + (size_t)L*UNITS, gabg + (size_t)L*UNITS, \
            tbgb + (size_t)L*UNITS, eleb + (size_t)L*UNITS, elab + (size_t)L*UNITS, \
            encb, Aout[L]
        if (L == 0)
            k_gated_fused<1,0,1><<<gemm_blocks, 512, 0, stream>>>(GATED_ARGS);
        else if (L == 1)
            k_gated_fused<0,1,1><<<gemm_blocks, 512, 0, stream>>>(GATED_ARGS);
        else
            k_gated_fused<0,1,0><<<gemm_blocks, 512, 0, stream>>>(GATED_ARGS);
        #undef GATED_ARGS
    }
    k_final<<<1024, 256, 0, stream>>>(aggA, fw1, fb1, fw2, fb2, anum, escl, eshf, out);
}

// Round 18
// 1171.571 us; speedup vs baseline: 1.5080x; 1.0545x over previous
//
#include <hip/hip_runtime.h>
#include <math.h>

#define UNITS   128
#define NRBF    10
#define SBF     9
#define NLAYERS 3
#define NELEM   95
#define NTOTAL  60000
#define NLOCAL  50000
#define NGHOST  10000
#define NEDGE   250000
#define NTRIPLE 1000000
#define CUTOFF  5.0f
#define TBCUT   4.0f
#define PI_F    3.14159265358979323846f
#define FSTR    424   // feat row stride in ushorts: 13 kb * 32 + 8 pad
#define MEDGE   64    // edges per gated block
#define SCHUNK  1024
#define NCHUNK  ((NEDGE + SCHUNK - 1)/SCHUNK)   // 245

typedef __attribute__((ext_vector_type(8))) short short8;
typedef __attribute__((ext_vector_type(4))) float f32x4;

__device__ __forceinline__ float sigm(float x){ return 1.0f/(1.0f+__expf(-x)); }
__device__ __forceinline__ float polycut(float r){
    float q = r*(1.0f/TBCUT);
    float q2 = q*q, q3 = q2*q;
    float p = 1.0f - 6.0f*q2*q3 + 15.0f*q2*q2 - 10.0f*q3;
    return (r <= TBCUT) ? p : 0.0f;
}
__device__ __forceinline__ ushort f2bf(float x){
    unsigned u = __float_as_uint(x);
    unsigned r = (u + 0x7fffu + ((u>>16)&1u)) >> 16;
    return (ushort)r;
}
__device__ __forceinline__ float bf2f(ushort h){
    return __uint_as_float(((unsigned)h) << 16);
}
__device__ __forceinline__ f32x4 splat4(float x){ f32x4 v = {x,x,x,x}; return v; }
__device__ __forceinline__ float gatef(float xm, float xg){
    float d = (1.0f+__expf(-xm))*(1.0f+__expf(-xg));
    return xm*__builtin_amdgcn_rcpf(d);
}

// ---------------- edge geometry + rbf ----------------
__global__ void k_edge_geom(const float* __restrict__ pos, const float* __restrict__ cell,
                            const float* __restrict__ pbc, const int* __restrict__ src,
                            const int* __restrict__ dst, const int* __restrict__ batch,
                            float* __restrict__ evec, float* __restrict__ elen,
                            float* __restrict__ rbf0){
    int e = blockIdx.x*blockDim.x + threadIdx.x;
    if (e >= NEDGE) return;
    int s = src[e], d = dst[e];
    int b = batch[s];
    const float* C = cell + b*9;
    float p0 = pbc[e*3+0], p1 = pbc[e*3+1], p2 = pbc[e*3+2];
    float vx = pos[s*3+0] - (pos[d*3+0] + p0*C[0] + p1*C[3] + p2*C[6]);
    float vy = pos[s*3+1] - (pos[d*3+1] + p0*C[1] + p1*C[4] + p2*C[7]);
    float vz = pos[s*3+2] - (pos[d*3+2] + p0*C[2] + p1*C[5] + p2*C[8]);
    float r = sqrtf(vx*vx + vy*vy + vz*vz);
    evec[e*3+0] = vx; evec[e*3+1] = vy; evec[e*3+2] = vz;
    elen[e] = r;
    #pragma unroll
    for (int i = 0; i < NRBF; i++){
        float mu = (CUTOFF/(NRBF-1))*i;
        float dm = r - mu;
        rbf0[e*NRBF + i] = __expf(-dm*dm*2.0f);
    }
}

// ---------------- atom embedding: bf16 mirror only (f32 path gathers embw directly) ----------------
__global__ void k_embed(const int* __restrict__ anum, const float* __restrict__ embw,
                        ushort* __restrict__ Ah){
    int t = blockIdx.x*blockDim.x + threadIdx.x;
    if (t >= NTOTAL*32) return;
    int a = t >> 5, q = t & 31;
    float4 v = ((const float4*)embw)[anum[a]*32 + q];
    ushort4 h;
    h.x = f2bf(v.x); h.y = f2bf(v.y); h.z = f2bf(v.z); h.w = f2bf(v.w);
    ((ushort4*)Ah)[t] = h;
}

// ---------------- ALL weight packing in one dispatch (blockIdx-range branch) ----------------
// main W: 3*4*12*8*64 = 73728 thr = 288 blk   (R17 BUG: wrote 1152 -> L up to 11, OOB reads of gewm -> HSA fault)
// ext: 3072 thr = 12 blk   aux: 4608 = 18 blk   encB: 512 = 2 blk   bias: 768 = 3 blk
// blocks [0,288) main  [288,300) ext  [300,318) aux  [318,320) encB  [320,323) bias
__global__ void k_pack_all(const float* __restrict__ gewm, const float* __restrict__ gewg,
                           const float* __restrict__ gawm, const float* __restrict__ gawg,
                           const float* __restrict__ tbg,  const float* __restrict__ encw,
                           const float* __restrict__ elew, const float* __restrict__ elaw,
                           const float* __restrict__ gebm, const float* __restrict__ gebg,
                           const float* __restrict__ tbb,  const float* __restrict__ encb,
                           ushort* __restrict__ wmain, ushort* __restrict__ wext,
                           ushort* __restrict__ waux,  ushort* __restrict__ wencb,
                           float* __restrict__ btot){
    int blk = blockIdx.x, tid = threadIdx.x;
    if (blk < 288){
        int t = blk*256 + tid;
        if (t >= 3*4*12*8*64) return;
        int lane = t & 63;
        int nt   = (t>>6) & 7;
        int rest = t >> 9;
        int kb   = rest % 12;
        int r2   = rest / 12;
        int mat  = r2 & 3;
        int L    = r2 >> 2;
        const float* src;
        if      (mat == 0) src = gewm;
        else if (mat == 1) src = gewg;
        else if (mat == 2) src = gawm;
        else               src = gawg;
        src += (size_t)L*384*128;
        int n = nt*16 + (lane & 15);
        int kbase = kb*32 + (lane>>4)*8;
        ushort* dst = wmain + (size_t)t*8;
        #pragma unroll
        for (int j = 0; j < 8; j++) dst[j] = f2bf(src[(size_t)(kbase+j)*128 + n]);
    } else if (blk < 300){
        int t = (blk-288)*256 + tid;
        if (t >= 3*2*512) return;
        int lane = t & 63;
        int nt   = (t>>6) & 7;
        int mat  = (t>>9) & 1;
        int L    = t >> 10;
        const float* W  = ((mat==0)? gewm : gewg) + (size_t)L*384*128;
        const float* tg = tbg + (size_t)L*SBF*UNITS;
        int n = nt*16 + (lane & 15);
        ushort* dst = wext + (size_t)t*8;
        #pragma unroll
        for (int j = 0; j < 8; j++){
            int k = (lane>>4)*8 + j;
            float v = 0.0f;
            if (k >= 10 && k <= 18){
                int s = k - 10;
                for (int kk = 0; kk < 128; kk++)
                    v = fmaf(tg[s*UNITS+kk], W[(size_t)(256+kk)*128 + n], v);
            } else if (k < 10 && L == 0){
                for (int kk = 0; kk < 128; kk++)
                    v = fmaf(encw[k*UNITS+kk], W[(size_t)(256+kk)*128 + n], v);
            }
            dst[j] = f2bf(v);
        }
    } else if (blk < 318){
        int t = (blk-300)*256 + tid;
        if (t >= 3*3*512) return;
        int lane = t & 63;
        int nt   = (t>>6) & 7;
        int rest = t >> 9;
        int mat  = rest % 3;
        int L    = rest / 3;
        int n = nt*16 + (lane & 15);
        ushort* dst = waux + (size_t)t*8;
        #pragma unroll
        for (int j = 0; j < 8; j++){
            int k = (lane>>4)*8 + j;
            float v = 0.0f;
            if (mat == 0){ if (k < 10) v = elew[(size_t)L*NRBF*UNITS + k*UNITS + n]; }
            else if (mat == 1){ if (k < 10) v = elaw[(size_t)L*NRBF*UNITS + k*UNITS + n]; }
            else { if (k >= 10 && k <= 18) v = tbg[(size_t)L*SBF*UNITS + (k-10)*UNITS + n]; }
            dst[j] = f2bf(v);
        }
    } else if (blk < 320){
        int t = (blk-318)*256 + tid;
        if (t >= 512) return;
        int lane = t & 63;
        int nt   = t >> 6;
        int n = nt*16 + (lane & 15);
        ushort* dst = wencb + (size_t)t*8;
        #pragma unroll
        for (int j = 0; j < 8; j++){
            int k = (lane>>4)*8 + j;
            float v = (k < 10) ? encw[k*UNITS + n] : 0.0f;
            dst[j] = f2bf(v);
        }
    } else {
        int t = (blk-320)*256 + tid;
        if (t >= 3*2*128) return;
        int n = t & 127;
        int mat = (t>>7) & 1;
        int L = t >> 8;
        const float* W = ((mat==0)? gewm : gewg) + (size_t)L*384*128;
        const float* be = ((mat==0)? gebm : gebg) + (size_t)L*UNITS;
        const float* tb = tbb + (size_t)L*UNITS;
        float v = be[n];
        for (int kk = 0; kk < 128; kk++){
            float f = tb[kk];
            if (L == 0) f += encb[kk];
            v = fmaf(f, W[(size_t)(256+kk)*128 + n], v);
        }
        btot[t] = v;
    }
}

// ---------------- per-layer: atom sbf mlp + seed aggOut (+ optional bf16 mirror) ----------------
// GATHER=1 (L0): read embw[anum[a]] directly, no embedF buffer. WAH: write aggAh mirror.
template<int GATHER, int WAH>
__global__ void k_tb_mlp(const float* __restrict__ Fin, const int* __restrict__ anum,
                         const float* __restrict__ embw,
                         const float* __restrict__ W, const float* __restrict__ b,
                         float* __restrict__ out, float* __restrict__ aggOut,
                         ushort* __restrict__ Ah){
    int a = blockIdx.x*blockDim.x + threadIdx.x;
    if (a >= NLOCAL) return;
    float acc[SBF];
    #pragma unroll
    for (int s = 0; s < SBF; s++) acc[s] = b[s];
    const float4* row4 = GATHER ? (const float4*)(embw + (size_t)anum[a]*UNITS)
                                : (const float4*)(Fin + (size_t)a*UNITS);
    float4* agg4 = (float4*)(aggOut + (size_t)a*UNITS);
    ushort4* ah4 = (ushort4*)(Ah + (size_t)a*UNITS);
    for (int k4 = 0; k4 < 32; k4++){
        float4 v = row4[k4];
        agg4[k4] = v;
        if (WAH){
            ushort4 h;
            h.x = f2bf(v.x); h.y = f2bf(v.y); h.z = f2bf(v.z); h.w = f2bf(v.w);
            ah4[k4] = h;
        }
        const float* w = W + (k4*4)*SBF;
        #pragma unroll
        for (int s = 0; s < SBF; s++){
            acc[s] = fmaf(v.x, w[s],        acc[s]);
            acc[s] = fmaf(v.y, w[s+SBF],    acc[s]);
            acc[s] = fmaf(v.z, w[s+2*SBF],  acc[s]);
            acc[s] = fmaf(v.w, w[s+3*SBF],  acc[s]);
        }
    }
    #pragma unroll
    for (int s = 0; s < SBF; s++) out[a*SBF + s] = sigm(acc[s]);
}

// ---------------- triples: single 1M pass (validity + append + hist) ----------------
__global__ void k_triple_pass1(const float* __restrict__ elen, const int* __restrict__ tbi,
                               int* __restrict__ cnt, int* __restrict__ u_ij,
                               int* __restrict__ u_ik, int* __restrict__ hist){
    int t = blockIdx.x*blockDim.x + threadIdx.x;
    int tc = min(t, NTRIPLE-1);
    int ij = tbi[2*tc], ik = tbi[2*tc+1];
    bool valid = (t < NTRIPLE) && (polycut(elen[ij])*polycut(elen[ik]) != 0.0f);

    __shared__ int wbase[4];
    __shared__ int gbase;
    int tid = threadIdx.x;
    int wid = tid >> 6, lid = tid & 63;
    unsigned long long m = __ballot(valid);
    int wpre = __popcll(m & ((1ull << lid) - 1ull));
    if (lid == 0) wbase[wid] = __popcll(m);
    __syncthreads();
    if (tid == 0){
        int s = 0;
        #pragma unroll
        for (int i = 0; i < 4; i++){ int v = wbase[i]; wbase[i] = s; s += v; }
        gbase = (s > 0) ? atomicAdd(cnt, s) : 0;
    }
    __syncthreads();
    if (valid){
        int idx = gbase + wbase[wid] + wpre;
        u_ij[idx] = ij;
        u_ik[idx] = ik;
        atomicAdd(&hist[ij], 1);
    }
}
// 3-phase parallel scan (R15 lesson: 1-block serial scan = 589us)
__global__ void k_scanA(const int* __restrict__ hist, int* __restrict__ toff,
                        int* __restrict__ bsum){
    __shared__ int sh[256];
    int b = blockIdx.x, tid = threadIdx.x;
    int base = b*SCHUNK + tid*4;
    int v0 = 0, v1 = 0, v2 = 0, v3 = 0;
    if (base+0 < NEDGE) v0 = hist[base+0];
    if (base+1 < NEDGE) v1 = hist[base+1];
    if (base+2 < NEDGE) v2 = hist[base+2];
    if (base+3 < NEDGE) v3 = hist[base+3];
    int tsum = v0+v1+v2+v3;
    sh[tid] = tsum;
    __syncthreads();
    for (int off = 1; off < 256; off <<= 1){
        int x = (tid >= off) ? sh[tid-off] : 0;
        __syncthreads();
        sh[tid] += x;
        __syncthreads();
    }
    int run = (tid == 0) ? 0 : sh[tid-1];
    if (tid == 255) bsum[b] = sh[255];
    if (base+0 < NEDGE) toff[base+0] = run; run += v0;
    if (base+1 < NEDGE) toff[base+1] = run; run += v1;
    if (base+2 < NEDGE) toff[base+2] = run; run += v2;
    if (base+3 < NEDGE) toff[base+3] = run;
}
__global__ void k_scanB(int* __restrict__ bsum, int* __restrict__ total){
    __shared__ int sh[256];
    int tid = threadIdx.x;
    int v = (tid < NCHUNK) ? bsum[tid] : 0;
    sh[tid] = v;
    __syncthreads();
    for (int off = 1; off < 256; off <<= 1){
        int x = (tid >= off) ? sh[tid-off] : 0;
        __syncthreads();
        sh[tid] += x;
        __syncthreads();
    }
    if (tid < NCHUNK) bsum[tid] = sh[tid] - v;   // exclusive
    if (tid == 255) *total = sh[255];
}
__global__ void k_scanC(int* __restrict__ toff, int* __restrict__ curs,
                        const int* __restrict__ bsum, const int* __restrict__ total){
    int i = blockIdx.x*blockDim.x + threadIdx.x;
    if (i < NEDGE){
        int v = toff[i] + bsum[i/SCHUNK];
        toff[i] = v;
        curs[i] = v;
    }
    if (i == 0) toff[NEDGE] = *total;
}
// pass 2: full geometry for the ~30k survivors only, scatter into CSR slots
__global__ void k_triple_pass2(const float* __restrict__ evec, const float* __restrict__ elen,
                               const int* __restrict__ esrc, const int* __restrict__ cnt,
                               const int* __restrict__ u_ij, const int* __restrict__ u_ik,
                               int* __restrict__ curs, int* __restrict__ t_ka,
                               float* __restrict__ t_cf){
    int n = *cnt;
    for (int t = blockIdx.x*blockDim.x + threadIdx.x; t < n; t += gridDim.x*blockDim.x){
        int ij = u_ij[t], ik = u_ik[t];
        float rij = elen[ij], rik = elen[ik];
        float cc = polycut(rij)*polycut(rik);
        float ax = evec[ij*3+0], ay = evec[ij*3+1], az = evec[ij*3+2];
        float bx = evec[ik*3+0], by = evec[ik*3+1], bz = evec[ik*3+2];
        float dot = ax*bx + ay*by + az*bz;
        float c = dot/(rij*rik + 1e-12f);
        c = fminf(fmaxf(c, -1.0f + 1e-7f), 1.0f - 1e-7f);
        float a0 = 1.0f, a1 = c, a2 = 2.0f*c*c - 1.0f;
        float x = rik*(PI_F/TBCUT);
        float s1, c1;
        __sincosf(x, &s1, &c1);
        float s2 = 2.0f*s1*c1;
        float s3 = s1*(3.0f - 4.0f*s1*s1);
        float inv = 1.0f/(rik + 1e-6f);
        float r0 = s1*inv, r1 = s2*inv, r2 = s3*inv;
        int pos = atomicAdd(&curs[ij], 1);
        t_ka[pos] = esrc[ik];
        float* d = t_cf + (size_t)pos*SBF;
        d[0] = r0*a0*cc; d[1] = r0*a1*cc; d[2] = r0*a2*cc;
        d[3] = r1*a0*cc; d[4] = r1*a1*cc; d[5] = r1*a2*cc;
        d[6] = r2*a0*cc; d[7] = r2*a1*cc; d[8] = r2*a2*cc;
    }
}

// ---------------- fused per-layer gated blocks (ge + ga), all-MFMA ----------------
// R12-proven config: 64 edges/block, 512 threads, src_s/dst_s index cache in LDS.
// ENC/GM/STORE compile-time. tb(9) per edge computed INLINE from triples CSR
// (avg ~0.2 triples/edge). Coalesced Eh writeback. NO launch_bounds (R5/R7).
template<int ENC, int GM, int STORE>
__global__
void k_gated_fused(const ushort* __restrict__ Ah, const int* __restrict__ gmap,
                   ushort* __restrict__ Eh,
                   const int* __restrict__ esrc, const int* __restrict__ edst,
                   const float* __restrict__ rbf0,
                   const int* __restrict__ toff, const int* __restrict__ t_ka,
                   const float* __restrict__ t_cf, const float* __restrict__ amlp,
                   const ushort* __restrict__ Wem, const ushort* __restrict__ Weg,
                   const ushort* __restrict__ Wam, const ushort* __restrict__ Wag,
                   const ushort* __restrict__ WxM, const ushort* __restrict__ WxG,
                   const ushort* __restrict__ Ble, const ushort* __restrict__ Bla,
                   const ushort* __restrict__ Bte, const ushort* __restrict__ Benc,
                   const float* __restrict__ btm, const float* __restrict__ btg,
                   const float* __restrict__ bam, const float* __restrict__ bag,
                   const float* __restrict__ tbb, const float* __restrict__ eleb,
                   const float* __restrict__ elab, const float* __restrict__ encb,
                   float* __restrict__ agg){
    __shared__ __align__(16) ushort feat_s[MEDGE*FSTR];
    __shared__ int src_s[MEDGE];
    __shared__ int dst_s[MEDGE];

    const int tid = threadIdx.x;
    const int e0  = blockIdx.x*MEDGE;

    if (tid < MEDGE){
        int e = min(e0 + tid, NEDGE-1);
        src_s[tid] = esrc[e];
        int d = edst[e];
        if (GM && d >= NLOCAL) d = gmap[d - NLOCAL];
        dst_s[tid] = d;
    }
    __syncthreads();

    // main staging: 64 rows x 48 short8 chunks, 6/thread
    #pragma unroll
    for (int j = 0; j < 6; j++){
        int idx = j*512 + tid;
        int m   = idx/48;
        int k8  = idx - m*48;
        short8 h;
        if (k8 < 16){
            h = *(const short8*)(Ah + (size_t)src_s[m]*UNITS + k8*8);
        } else if (k8 < 32){
            h = *(const short8*)(Ah + (size_t)dst_s[m]*UNITS + (k8-16)*8);
        } else if (ENC){
            short8 z = {0,0,0,0,0,0,0,0};
            h = z;
        } else {
            int e = min(e0 + m, NEDGE-1);
            h = *(const short8*)(Eh + (size_t)e*UNITS + (k8-32)*8);
        }
        *(short8*)&feat_s[m*FSTR + k8*8] = h;
    }
    // aux staging: thread m builds its edge's [rbf(10) | tb(9) | 0..] row
    if (tid < MEDGE){
        int e = min(e0 + tid, NEDGE-1);
        float tb[SBF];
        #pragma unroll
        for (int s = 0; s < SBF; s++) tb[s] = 0.0f;
        int beg = toff[e], end = toff[e+1];
        for (int t = beg; t < end; t++){
            const float* cf = t_cf + (size_t)t*SBF;
            const float* am = amlp + (size_t)t_ka[t]*SBF;
            #pragma unroll
            for (int s = 0; s < SBF; s++) tb[s] = fmaf(cf[s], am[s], tb[s]);
        }
        ushort row[32];
        #pragma unroll
        for (int k = 0; k < 10; k++) row[k] = f2bf(rbf0[(size_t)e*NRBF + k]);
        #pragma unroll
        for (int s = 0; s < SBF; s++) row[10+s] = f2bf(tb[s]);
        #pragma unroll
        for (int k = 19; k < 32; k++) row[k] = 0;
        #pragma unroll
        for (int j8 = 0; j8 < 4; j8++)
            *(short8*)&feat_s[tid*FSTR + 384 + j8*8] = *(const short8*)&row[j8*8];
    }
    __syncthreads();

    const int lane = tid & 63;
    const int w    = tid >> 6;
    const int quad = lane >> 4;
    const int l15  = lane & 15;
    const int c    = w*16 + l15;

    // ---------------- Phase 1: ge GEMM (kb0..12) + te/le (+enc) aux ----------------
    f32x4 acc_em[4], acc_eg[4], acc_te[4], acc_le[4], acc_en[ENC ? 4 : 1];
    {
        float bm = btm[c], bg = btg[c], tb = tbb[c], le = eleb[c];
        #pragma unroll
        for (int mt = 0; mt < 4; mt++){
            acc_em[mt] = splat4(bm); acc_eg[mt] = splat4(bg);
            acc_te[mt] = splat4(tb); acc_le[mt] = splat4(le);
        }
        if (ENC){
            float eb = encb[c];
            #pragma unroll
            for (int mt = 0; mt < 4; mt++) acc_en[mt] = splat4(eb);
        }
    }
    const ushort* abase = feat_s + l15*FSTR + quad*8;

    for (int ks = 0; ks < 12; ks++){
        short8 a[4];
        #pragma unroll
        for (int mt = 0; mt < 4; mt++)
            a[mt] = *(const short8*)(abase + mt*16*FSTR + ks*32);
        size_t boff = ((size_t)(ks*8 + w)*64 + lane)*8;
        short8 b_em = *(const short8*)(Wem + boff);
        short8 b_eg = *(const short8*)(Weg + boff);
        #pragma unroll
        for (int mt = 0; mt < 4; mt++){
            acc_em[mt] = __builtin_amdgcn_mfma_f32_16x16x32_bf16(a[mt], b_em, acc_em[mt], 0, 0, 0);
            acc_eg[mt] = __builtin_amdgcn_mfma_f32_16x16x32_bf16(a[mt], b_eg, acc_eg[mt], 0, 0, 0);
        }
    }
    {   // kb12 aux fragment
        size_t bx = ((size_t)w*64 + lane)*8;
        short8 b_xm = *(const short8*)(WxM + bx);
        short8 b_xg = *(const short8*)(WxG + bx);
        short8 b_te = *(const short8*)(Bte + bx);
        short8 b_le = *(const short8*)(Ble + bx);
        #pragma unroll
        for (int mt = 0; mt < 4; mt++){
            short8 ax = *(const short8*)(abase + mt*16*FSTR + 384);
            acc_em[mt] = __builtin_amdgcn_mfma_f32_16x16x32_bf16(ax, b_xm, acc_em[mt], 0, 0, 0);
            acc_eg[mt] = __builtin_amdgcn_mfma_f32_16x16x32_bf16(ax, b_xg, acc_eg[mt], 0, 0, 0);
            acc_te[mt] = __builtin_amdgcn_mfma_f32_16x16x32_bf16(ax, b_te, acc_te[mt], 0, 0, 0);
            acc_le[mt] = __builtin_amdgcn_mfma_f32_16x16x32_bf16(ax, b_le, acc_le[mt], 0, 0, 0);
        }
        if (ENC){
            short8 b_en = *(const short8*)(Benc + bx);
            #pragma unroll
            for (int mt = 0; mt < 4; mt++){
                short8 ax = *(const short8*)(abase + mt*16*FSTR + 384);
                acc_en[mt] = __builtin_amdgcn_mfma_f32_16x16x32_bf16(ax, b_en, acc_en[mt], 0, 0, 0);
            }
        }
    }

    // ---------------- Epilogue 1: E_new = E_old + tbgate + gate*el_e ----------------
    __syncthreads();
    #pragma unroll
    for (int mt = 0; mt < 4; mt++){
        #pragma unroll
        for (int r = 0; r < 4; r++){
            int ml = mt*16 + quad*4 + r;
            int e  = e0 + ml;
            if (e >= NEDGE) continue;
            float gate = gatef(acc_em[mt][r], acc_eg[mt][r]);
            float eold = ENC ? acc_en[mt][r] : bf2f(feat_s[ml*FSTR + 256 + c]);
            float enew = eold + acc_te[mt][r] + gate*acc_le[mt][r];
            feat_s[ml*FSTR + 256 + c] = f2bf(enew);
        }
    }
    __syncthreads();

    // coalesced Eh writeback from LDS E-region (2 x 16B stores/thread)
    if (STORE){
        #pragma unroll
        for (int j = 0; j < 2; j++){
            int idx = j*512 + tid;
            int row = idx >> 4;
            int q8  = idx & 15;
            int e   = e0 + row;
            if (e < NEDGE)
                *(short8*)(Eh + (size_t)e*UNITS + q8*8)
                    = *(const short8*)&feat_s[row*FSTR + 256 + q8*8];
        }
    }

    // ---------------- Phase 2: ga GEMM (full kb0..11 on E_new) + la aux ----------------
    f32x4 acc_am[4], acc_ag[4], acc_la[4];
    {
        float bm = bam[c], bg = bag[c], lb = elab[c];
        #pragma unroll
        for (int mt = 0; mt < 4; mt++){
            acc_am[mt] = splat4(bm); acc_ag[mt] = splat4(bg); acc_la[mt] = splat4(lb);
        }
    }
    for (int ks = 0; ks < 12; ks++){
        short8 a[4];
        #pragma unroll
        for (int mt = 0; mt < 4; mt++)
            a[mt] = *(const short8*)(abase + mt*16*FSTR + ks*32);
        size_t boff = ((size_t)(ks*8 + w)*64 + lane)*8;
        short8 b_am = *(const short8*)(Wam + boff);
        short8 b_ag = *(const short8*)(Wag + boff);
        #pragma unroll
        for (int mt = 0; mt < 4; mt++){
            acc_am[mt] = __builtin_amdgcn_mfma_f32_16x16x32_bf16(a[mt], b_am, acc_am[mt], 0, 0, 0);
            acc_ag[mt] = __builtin_amdgcn_mfma_f32_16x16x32_bf16(a[mt], b_ag, acc_ag[mt], 0, 0, 0);
        }
    }
    {
        size_t bx = ((size_t)w*64 + lane)*8;
        short8 b_la = *(const short8*)(Bla + bx);
        #pragma unroll
        for (int mt = 0; mt < 4; mt++){
            short8 ax = *(const short8*)(abase + mt*16*FSTR + 384);
            acc_la[mt] = __builtin_amdgcn_mfma_f32_16x16x32_bf16(ax, b_la, acc_la[mt], 0, 0, 0);
        }
    }

    // ---------------- Epilogue 2: f32 atomics into agg[src] ----------------
    #pragma unroll
    for (int mt = 0; mt < 4; mt++){
        #pragma unroll
        for (int r = 0; r < 4; r++){
            int ml = mt*16 + quad*4 + r;
            int e  = e0 + ml;
            if (e >= NEDGE) continue;
            float gate = gatef(acc_am[mt][r], acc_ag[mt][r]);
            atomicAdd(&agg[(size_t)src_s[ml]*UNITS + c], gate*acc_la[mt][r]);
        }
    }
}

// ---------------- final readout + global sum ----------------
__global__ void k_final(const float* __restrict__ A, const float* __restrict__ W1,
                        const float* __restrict__ b1, const float* __restrict__ W2,
                        const float* __restrict__ b2, const int* __restrict__ anum,
                        const float* __restrict__ escl, const float* __restrict__ eshf,
                        float* __restrict__ out){
    __shared__ float red[256];
    const int tid  = threadIdx.x;
    const int c    = tid & 127;
    const int half = tid >> 7;
    float b1c = b1[c];
    float w2c = W2[c];
    float b2v = b2[0];
    float tpart = 0.0f;
    const int npairs = NLOCAL/2;
    for (int p = blockIdx.x; p < npairs; p += gridDim.x){
        int a = 2*p + half;
        const float* h = A + (size_t)a*UNITS;
        float acc = b1c;
        for (int k = 0; k < UNITS; k++)
            acc = fmaf(h[k], W1[k*UNITS + c], acc);
        float hid = acc/(1.0f+__expf(-acc));
        int z = anum[a];
        float sc = escl[z];
        tpart = fmaf(sc*hid, w2c, tpart);
        if (c == 0) tpart += sc*b2v + eshf[z];
    }
    red[tid] = tpart;
    __syncthreads();
    for (int s = 128; s > 0; s >>= 1){
        if (tid < s) red[tid] += red[tid + s];
        __syncthreads();
    }
    if (tid == 0) atomicAdd(out, red[0]);
}

extern "C" void kernel_launch(void* const* d_in, const int* in_sizes, int n_in,
                              void* d_out, int out_size, void* d_ws, size_t ws_size,
                              hipStream_t stream){
    const int*   anum  = (const int*)d_in[0];
    const float* pos   = (const float*)d_in[1];
    const float* cell  = (const float*)d_in[2];
    const float* pbc   = (const float*)d_in[3];
    const int*   esrc  = (const int*)d_in[4];
    const int*   edst  = (const int*)d_in[5];
    const int*   tbi   = (const int*)d_in[6];
    const int*   batch = (const int*)d_in[7];
    const int*   gmap  = (const int*)d_in[8];
    const float* embw  = (const float*)d_in[10];
    const float* encw  = (const float*)d_in[11];
    const float* encb  = (const float*)d_in[12];
    const float* tbaw  = (const float*)d_in[13];
    const float* tbab  = (const float*)d_in[14];
    const float* tbgw  = (const float*)d_in[15];
    const float* tbgb  = (const float*)d_in[16];
    const float* gewm  = (const float*)d_in[17];
    const float* gebm  = (const float*)d_in[18];
    const float* gewg  = (const float*)d_in[19];
    const float* gebg  = (const float*)d_in[20];
    const float* elew  = (const float*)d_in[21];
    const float* eleb  = (const float*)d_in[22];
    const float* gawm  = (const float*)d_in[23];
    const float* gabm  = (const float*)d_in[24];
    const float* gawg  = (const float*)d_in[25];
    const float* gabg  = (const float*)d_in[26];
    const float* elaw  = (const float*)d_in[27];
    const float* elab  = (const float*)d_in[28];
    const float* fw1   = (const float*)d_in[29];
    const float* fb1   = (const float*)d_in[30];
    const float* fw2   = (const float*)d_in[31];
    const float* fb2   = (const float*)d_in[32];
    const float* escl  = (const float*)d_in[33];
    const float* eshf  = (const float*)d_in[34];
    (void)in_sizes; (void)n_in; (void)out_size; (void)ws_size;

    float* ws     = (float*)d_ws;
    float* aggA   = ws;                                   // NLOCAL*128 f32
    float* aggB   = aggA   + (size_t)NLOCAL*UNITS;        // NLOCAL*128 f32
    float* evec   = aggB   + (size_t)NLOCAL*UNITS;        // NEDGE*3
    float* elen   = evec   + (size_t)NEDGE*3;             // NEDGE
    float* rbf0   = elen   + (size_t)NEDGE;               // NEDGE*10
    float* amlp   = rbf0   + (size_t)NEDGE*NRBF;          // NLOCAL*9
    float* btot   = amlp   + (size_t)NLOCAL*SBF;          // 3*2*128
    int*   hist   = (int*)(btot + 3*2*128);               // NEDGE
    int*   tcnt   = hist + NEDGE;                         // 4 (contiguous w/ hist: one memset)
    int*   toff   = tcnt + 4;                             // NEDGE+1
    int*   curs   = toff + NEDGE + 1;                     // NEDGE (+pad)
    int*   bsum   = curs + NEDGE + 3;                     // NCHUNK (+pad)
    int*   total  = bsum + NCHUNK + 1;                    // 1 (+pad)
    int*   u_ij   = total + 4;                            // NTRIPLE
    int*   u_ik   = u_ij + NTRIPLE;                       // NTRIPLE
    int*   t_ka   = u_ik + NTRIPLE;                       // NTRIPLE
    float* t_cf   = (float*)(t_ka + NTRIPLE);             // 9*NTRIPLE (AoS)
    ushort* edgeEh = (ushort*)(t_cf + (size_t)9*NTRIPLE); // NEDGE*128 bf16
    ushort* embedAh = edgeEh + (size_t)NEDGE*UNITS;       // NTOTAL*128 bf16
    ushort* aggAh   = embedAh + (size_t)NTOTAL*UNITS;     // NLOCAL*128 bf16
    ushort* wmain  = aggAh + (size_t)NLOCAL*UNITS;        // 3*4*49152
    ushort* wext   = wmain + (size_t)3*4*49152;           // 3*2*4096
    ushort* waux   = wext  + (size_t)3*2*4096;            // 3*3*4096
    ushort* wencb  = waux  + (size_t)3*3*4096;            // 4096

    float* out = (float*)d_out;
    hipMemsetAsync(out, 0, sizeof(float), stream);
    hipMemsetAsync(hist, 0, (NEDGE+4)*sizeof(int), stream);   // hist + tcnt

    k_pack_all<<<323, 256, 0, stream>>>(gewm, gewg, gawm, gawg, tbgw, encw,
                                        elew, elaw, gebm, gebg, tbgb, encb,
                                        wmain, wext, waux, wencb, btot);
    k_edge_geom<<<(NEDGE+255)/256, 256, 0, stream>>>(pos, cell, pbc, esrc, edst, batch,
                                                     evec, elen, rbf0);
    k_embed<<<(NTOTAL*32+255)/256, 256, 0, stream>>>(anum, embw, embedAh);
    // triples: single 1M pass (validity+append+hist) -> scan -> geometry for ~30k
    k_triple_pass1<<<(NTRIPLE+255)/256, 256, 0, stream>>>(elen, tbi, tcnt, u_ij, u_ik, hist);
    k_scanA<<<NCHUNK, 256, 0, stream>>>(hist, toff, bsum);
    k_scanB<<<1, 256, 0, stream>>>(bsum, total);
    k_scanC<<<(NEDGE+255)/256, 256, 0, stream>>>(toff, curs, bsum, total);
    k_triple_pass2<<<256, 256, 0, stream>>>(evec, elen, esrc, tcnt, u_ij, u_ik,
                                            curs, t_ka, t_cf);

    const int gemm_blocks = (NEDGE + MEDGE - 1)/MEDGE;
    float*  Fin[3]  = { nullptr, aggA, aggB };
    float*  Aout[3] = { aggA,    aggB, aggA };
    for (int L = 0; L < NLAYERS; L++){
        const ushort* wmL = wmain + (size_t)L*4*49152;
        const ushort* wxL = wext  + (size_t)L*2*4096;
        const ushort* waL = waux  + (size_t)L*3*4096;
        if (L == 0)
            k_tb_mlp<1,0><<<(NLOCAL+255)/256, 256, 0, stream>>>(nullptr, anum, embw,
                tbaw + (size_t)L*UNITS*SBF, tbab + (size_t)L*SBF, amlp, Aout[L], aggAh);
        else
            k_tb_mlp<0,1><<<(NLOCAL+255)/256, 256, 0, stream>>>(Fin[L], anum, embw,
                tbaw + (size_t)L*UNITS*SBF, tbab + (size_t)L*SBF, amlp, Aout[L], aggAh);
        const ushort* AhL = (L == 0) ? embedAh : aggAh;
        #define GATED_ARGS AhL, gmap, edgeEh, esrc, edst, rbf0, toff, t_ka, t_cf, amlp, \
            wmL + 0*49152, wmL + 1*49152, wmL + 2*49152, wmL + 3*49152, \
            wxL + 0*4096,  wxL + 1*4096, \
            waL + 0*4096,  waL + 1*4096, waL + 2*4096, wencb, \
            btot + (size_t)L*2*128, btot + (size_t)L*2*128 + 128, \
            gabm + (size_t)L*UNITS, gabg + (size_t)L*UNITS, \
            tbgb + (size_t)L*UNITS, eleb + (size_t)L*UNITS, elab + (size_t)L*UNITS, \
            encb, Aout[L]
        if (L == 0)
            k_gated_fused<1,0,1><<<gemm_blocks, 512, 0, stream>>>(GATED_ARGS);
        else if (L == 1)
            k_gated_fused<0,1,1><<<gemm_blocks, 512, 0, stream>>>(GATED_ARGS);
        else
            k_gated_fused<0,1,0><<<gemm_blocks, 512, 0, stream>>>(GATED_ARGS);
        #undef GATED_ARGS
    }
    k_final<<<1024, 256, 0, stream>>>(aggA, fw1, fb1, fw2, fb2, anum, escl, eshf, out);
}

// Round 19
// 1000.167 us; speedup vs baseline: 1.7665x; 1.1714x over previous
//
#include <hip/hip_runtime.h>
#include <math.h>

#define UNITS   128
#define NRBF    10
#define SBF     9
#define NLAYERS 3
#define NELEM   95
#define NTOTAL  60000
#define NLOCAL  50000
#define NGHOST  10000
#define NEDGE   250000
#define NTRIPLE 1000000
#define CUTOFF  5.0f
#define TBCUT   4.0f
#define PI_F    3.14159265358979323846f
#define FSTR    424   // feat row stride in ushorts: 13 kb * 32 + 8 pad
#define MEDGE   64    // edges per gated block
#define SCHUNK  1024
#define NCHUNK  ((NEDGE + SCHUNK - 1)/SCHUNK)   // 245

// prologue block ranges
#define PB_MAIN 288              // 3*4*12*8*64/256
#define PB_EXT  12
#define PB_AUX  18
#define PB_ENC  2
#define PB_BIAS 3
#define PB_W1   8                // 4*8*64/256 * 8j -> 2048 thr
#define PB_PACK (PB_MAIN+PB_EXT+PB_AUX+PB_ENC+PB_BIAS+PB_W1)   // 331
#define PB_GEOM 977
#define PB_EMB  7500
#define PB_ALL  (PB_PACK+PB_GEOM+PB_EMB)   // 8808

typedef __attribute__((ext_vector_type(8))) short short8;
typedef __attribute__((ext_vector_type(4))) float f32x4;

__device__ __forceinline__ float sigm(float x){ return 1.0f/(1.0f+__expf(-x)); }
__device__ __forceinline__ float polycut(float r){
    float q = r*(1.0f/TBCUT);
    float q2 = q*q, q3 = q2*q;
    float p = 1.0f - 6.0f*q2*q3 + 15.0f*q2*q2 - 10.0f*q3;
    return (r <= TBCUT) ? p : 0.0f;
}
__device__ __forceinline__ ushort f2bf(float x){
    unsigned u = __float_as_uint(x);
    unsigned r = (u + 0x7fffu + ((u>>16)&1u)) >> 16;
    return (ushort)r;
}
__device__ __forceinline__ float bf2f(ushort h){
    return __uint_as_float(((unsigned)h) << 16);
}
__device__ __forceinline__ f32x4 splat4(float x){ f32x4 v = {x,x,x,x}; return v; }
__device__ __forceinline__ float gatef(float xm, float xg){
    float d = (1.0f+__expf(-xm))*(1.0f+__expf(-xg));
    return xm*__builtin_amdgcn_rcpf(d);
}

// ---------------- mega-prologue: all packing + edge geometry + atom embed ----------------
__global__ void k_prologue(const float* __restrict__ gewm, const float* __restrict__ gewg,
                           const float* __restrict__ gawm, const float* __restrict__ gawg,
                           const float* __restrict__ tbg,  const float* __restrict__ encw,
                           const float* __restrict__ elew, const float* __restrict__ elaw,
                           const float* __restrict__ gebm, const float* __restrict__ gebg,
                           const float* __restrict__ tbb,  const float* __restrict__ encb,
                           const float* __restrict__ fw1,
                           const float* __restrict__ pos, const float* __restrict__ cell,
                           const float* __restrict__ pbc, const int* __restrict__ esrc,
                           const int* __restrict__ edst, const int* __restrict__ batch,
                           const int* __restrict__ anum, const float* __restrict__ embw,
                           ushort* __restrict__ wmain, ushort* __restrict__ wext,
                           ushort* __restrict__ waux,  ushort* __restrict__ wencb,
                           ushort* __restrict__ wfin,  float* __restrict__ btot,
                           float* __restrict__ evec, float* __restrict__ elen,
                           float* __restrict__ rbf0, ushort* __restrict__ Ah){
    int blk = blockIdx.x, tid = threadIdx.x;
    if (blk < PB_MAIN){
        int t = blk*256 + tid;
        if (t >= 3*4*12*8*64) return;
        int lane = t & 63;
        int nt   = (t>>6) & 7;
        int rest = t >> 9;
        int kb   = rest % 12;
        int r2   = rest / 12;
        int mat  = r2 & 3;
        int L    = r2 >> 2;
        const float* src;
        if      (mat == 0) src = gewm;
        else if (mat == 1) src = gewg;
        else if (mat == 2) src = gawm;
        else               src = gawg;
        src += (size_t)L*384*128;
        int n = nt*16 + (lane & 15);
        int kbase = kb*32 + (lane>>4)*8;
        ushort* dst = wmain + (size_t)t*8;
        #pragma unroll
        for (int j = 0; j < 8; j++) dst[j] = f2bf(src[(size_t)(kbase+j)*128 + n]);
    } else if (blk < PB_MAIN+PB_EXT){
        int t = (blk-PB_MAIN)*256 + tid;
        if (t >= 3*2*512) return;
        int lane = t & 63;
        int nt   = (t>>6) & 7;
        int mat  = (t>>9) & 1;
        int L    = t >> 10;
        const float* W  = ((mat==0)? gewm : gewg) + (size_t)L*384*128;
        const float* tg = tbg + (size_t)L*SBF*UNITS;
        int n = nt*16 + (lane & 15);
        ushort* dst = wext + (size_t)t*8;
        #pragma unroll
        for (int j = 0; j < 8; j++){
            int k = (lane>>4)*8 + j;
            float v = 0.0f;
            if (k >= 10 && k <= 18){
                int s = k - 10;
                for (int kk = 0; kk < 128; kk++)
                    v = fmaf(tg[s*UNITS+kk], W[(size_t)(256+kk)*128 + n], v);
            } else if (k < 10 && L == 0){
                for (int kk = 0; kk < 128; kk++)
                    v = fmaf(encw[k*UNITS+kk], W[(size_t)(256+kk)*128 + n], v);
            }
            dst[j] = f2bf(v);
        }
    } else if (blk < PB_MAIN+PB_EXT+PB_AUX){
        int t = (blk-PB_MAIN-PB_EXT)*256 + tid;
        if (t >= 3*3*512) return;
        int lane = t & 63;
        int nt   = (t>>6) & 7;
        int rest = t >> 9;
        int mat  = rest % 3;
        int L    = rest / 3;
        int n = nt*16 + (lane & 15);
        ushort* dst = waux + (size_t)t*8;
        #pragma unroll
        for (int j = 0; j < 8; j++){
            int k = (lane>>4)*8 + j;
            float v = 0.0f;
            if (mat == 0){ if (k < 10) v = elew[(size_t)L*NRBF*UNITS + k*UNITS + n]; }
            else if (mat == 1){ if (k < 10) v = elaw[(size_t)L*NRBF*UNITS + k*UNITS + n]; }
            else { if (k >= 10 && k <= 18) v = tbg[(size_t)L*SBF*UNITS + (k-10)*UNITS + n]; }
            dst[j] = f2bf(v);
        }
    } else if (blk < PB_MAIN+PB_EXT+PB_AUX+PB_ENC){
        int t = (blk-PB_MAIN-PB_EXT-PB_AUX)*256 + tid;
        if (t >= 512) return;
        int lane = t & 63;
        int nt   = t >> 6;
        int n = nt*16 + (lane & 15);
        ushort* dst = wencb + (size_t)t*8;
        #pragma unroll
        for (int j = 0; j < 8; j++){
            int k = (lane>>4)*8 + j;
            float v = (k < 10) ? encw[k*UNITS + n] : 0.0f;
            dst[j] = f2bf(v);
        }
    } else if (blk < PB_MAIN+PB_EXT+PB_AUX+PB_ENC+PB_BIAS){
        int t = (blk-PB_MAIN-PB_EXT-PB_AUX-PB_ENC)*256 + tid;
        if (t >= 3*2*128) return;
        int n = t & 127;
        int mat = (t>>7) & 1;
        int L = t >> 8;
        const float* W = ((mat==0)? gewm : gewg) + (size_t)L*384*128;
        const float* be = ((mat==0)? gebm : gebg) + (size_t)L*UNITS;
        const float* tb = tbb + (size_t)L*UNITS;
        float v = be[n];
        for (int kk = 0; kk < 128; kk++){
            float f = tb[kk];
            if (L == 0) f += encb[kk];
            v = fmaf(f, W[(size_t)(256+kk)*128 + n], v);
        }
        btot[t] = v;
    } else if (blk < PB_PACK){
        int t = (blk-PB_MAIN-PB_EXT-PB_AUX-PB_ENC-PB_BIAS)*256 + tid;
        if (t >= 4*8*64) return;
        int lane = t & 63;
        int nt   = (t>>6) & 7;
        int kb   = t >> 9;
        int n = nt*16 + (lane & 15);
        int kbase = kb*32 + (lane>>4)*8;
        ushort* dst = wfin + (size_t)t*8;
        #pragma unroll
        for (int j = 0; j < 8; j++) dst[j] = f2bf(fw1[(size_t)(kbase+j)*128 + n]);
    } else if (blk < PB_PACK+PB_GEOM){
        int e = (blk-PB_PACK)*256 + tid;
        if (e >= NEDGE) return;
        int s = esrc[e], d = edst[e];
        int b = batch[s];
        const float* C = cell + b*9;
        float p0 = pbc[e*3+0], p1 = pbc[e*3+1], p2 = pbc[e*3+2];
        float vx = pos[s*3+0] - (pos[d*3+0] + p0*C[0] + p1*C[3] + p2*C[6]);
        float vy = pos[s*3+1] - (pos[d*3+1] + p0*C[1] + p1*C[4] + p2*C[7]);
        float vz = pos[s*3+2] - (pos[d*3+2] + p0*C[2] + p1*C[5] + p2*C[8]);
        float r = sqrtf(vx*vx + vy*vy + vz*vz);
        evec[e*3+0] = vx; evec[e*3+1] = vy; evec[e*3+2] = vz;
        elen[e] = r;
        #pragma unroll
        for (int i = 0; i < NRBF; i++){
            float mu = (CUTOFF/(NRBF-1))*i;
            float dm = r - mu;
            rbf0[e*NRBF + i] = __expf(-dm*dm*2.0f);
        }
    } else {
        int t = (blk-PB_PACK-PB_GEOM)*256 + tid;
        if (t >= NTOTAL*32) return;
        int a = t >> 5, q = t & 31;
        float4 v = ((const float4*)embw)[anum[a]*32 + q];
        ushort4 h;
        h.x = f2bf(v.x); h.y = f2bf(v.y); h.z = f2bf(v.z); h.w = f2bf(v.w);
        ((ushort4*)Ah)[t] = h;
    }
}

// ---------------- per-layer: atom sbf mlp + seed aggOut (+ optional bf16 mirror) ----------------
template<int GATHER, int WAH>
__global__ void k_tb_mlp(const float* __restrict__ Fin, const int* __restrict__ anum,
                         const float* __restrict__ embw,
                         const float* __restrict__ W, const float* __restrict__ b,
                         float* __restrict__ out, float* __restrict__ aggOut,
                         ushort* __restrict__ Ah){
    int a = blockIdx.x*blockDim.x + threadIdx.x;
    if (a >= NLOCAL) return;
    float acc[SBF];
    #pragma unroll
    for (int s = 0; s < SBF; s++) acc[s] = b[s];
    const float4* row4 = GATHER ? (const float4*)(embw + (size_t)anum[a]*UNITS)
                                : (const float4*)(Fin + (size_t)a*UNITS);
    float4* agg4 = (float4*)(aggOut + (size_t)a*UNITS);
    ushort4* ah4 = (ushort4*)(Ah + (size_t)a*UNITS);
    for (int k4 = 0; k4 < 32; k4++){
        float4 v = row4[k4];
        agg4[k4] = v;
        if (WAH){
            ushort4 h;
            h.x = f2bf(v.x); h.y = f2bf(v.y); h.z = f2bf(v.z); h.w = f2bf(v.w);
            ah4[k4] = h;
        }
        const float* w = W + (k4*4)*SBF;
        #pragma unroll
        for (int s = 0; s < SBF; s++){
            acc[s] = fmaf(v.x, w[s],        acc[s]);
            acc[s] = fmaf(v.y, w[s+SBF],    acc[s]);
            acc[s] = fmaf(v.z, w[s+2*SBF],  acc[s]);
            acc[s] = fmaf(v.w, w[s+3*SBF],  acc[s]);
        }
    }
    #pragma unroll
    for (int s = 0; s < SBF; s++) out[a*SBF + s] = sigm(acc[s]);
}

// ---------------- triples: single 1M pass (validity + append + hist) ----------------
__global__ void k_triple_pass1(const float* __restrict__ elen, const int* __restrict__ tbi,
                               int* __restrict__ cnt, int* __restrict__ u_ij,
                               int* __restrict__ u_ik, int* __restrict__ hist){
    int t = blockIdx.x*blockDim.x + threadIdx.x;
    int tc = min(t, NTRIPLE-1);
    int ij = tbi[2*tc], ik = tbi[2*tc+1];
    bool valid = (t < NTRIPLE) && (polycut(elen[ij])*polycut(elen[ik]) != 0.0f);

    __shared__ int wbase[4];
    __shared__ int gbase;
    int tid = threadIdx.x;
    int wid = tid >> 6, lid = tid & 63;
    unsigned long long m = __ballot(valid);
    int wpre = __popcll(m & ((1ull << lid) - 1ull));
    if (lid == 0) wbase[wid] = __popcll(m);
    __syncthreads();
    if (tid == 0){
        int s = 0;
        #pragma unroll
        for (int i = 0; i < 4; i++){ int v = wbase[i]; wbase[i] = s; s += v; }
        gbase = (s > 0) ? atomicAdd(cnt, s) : 0;
    }
    __syncthreads();
    if (valid){
        int idx = gbase + wbase[wid] + wpre;
        u_ij[idx] = ij;
        u_ik[idx] = ik;
        atomicAdd(&hist[ij], 1);
    }
}
// fused scanA+scanB: per-chunk LDS scan; last block (done-counter) scans chunk totals
__global__ void k_scanAB(const int* __restrict__ hist, int* __restrict__ toff,
                         int* __restrict__ bsum, int* __restrict__ total,
                         int* __restrict__ done){
    __shared__ int sh[256];
    __shared__ int amlast;
    int b = blockIdx.x, tid = threadIdx.x;
    int base = b*SCHUNK + tid*4;
    int v0 = 0, v1 = 0, v2 = 0, v3 = 0;
    if (base+0 < NEDGE) v0 = hist[base+0];
    if (base+1 < NEDGE) v1 = hist[base+1];
    if (base+2 < NEDGE) v2 = hist[base+2];
    if (base+3 < NEDGE) v3 = hist[base+3];
    int tsum = v0+v1+v2+v3;
    sh[tid] = tsum;
    __syncthreads();
    for (int off = 1; off < 256; off <<= 1){
        int x = (tid >= off) ? sh[tid-off] : 0;
        __syncthreads();
        sh[tid] += x;
        __syncthreads();
    }
    int run = (tid == 0) ? 0 : sh[tid-1];
    if (base+0 < NEDGE) toff[base+0] = run; run += v0;
    if (base+1 < NEDGE) toff[base+1] = run; run += v1;
    if (base+2 < NEDGE) toff[base+2] = run; run += v2;
    if (base+3 < NEDGE) toff[base+3] = run;
    if (tid == 255){
        bsum[b] = sh[255];
        __threadfence();                       // release bsum[b]
        amlast = (atomicAdd(done, 1) == gridDim.x - 1);
    }
    __syncthreads();
    if (amlast){
        __threadfence();                       // acquire all bsum[]
        int v = (tid < NCHUNK) ? bsum[tid] : 0;
        __syncthreads();
        sh[tid] = v;
        __syncthreads();
        for (int off = 1; off < 256; off <<= 1){
            int x = (tid >= off) ? sh[tid-off] : 0;
            __syncthreads();
            sh[tid] += x;
            __syncthreads();
        }
        if (tid < NCHUNK) bsum[tid] = sh[tid] - v;   // exclusive
        if (tid == 255) *total = sh[255];
    }
}
__global__ void k_scanC(int* __restrict__ toff, int* __restrict__ curs,
                        const int* __restrict__ bsum, const int* __restrict__ total){
    int i = blockIdx.x*blockDim.x + threadIdx.x;
    if (i < NEDGE){
        int v = toff[i] + bsum[i/SCHUNK];
        toff[i] = v;
        curs[i] = v;
    }
    if (i == 0) toff[NEDGE] = *total;
}
// pass 2: full geometry for the ~30k survivors only, scatter into CSR slots
__global__ void k_triple_pass2(const float* __restrict__ evec, const float* __restrict__ elen,
                               const int* __restrict__ esrc, const int* __restrict__ cnt,
                               const int* __restrict__ u_ij, const int* __restrict__ u_ik,
                               int* __restrict__ curs, int* __restrict__ t_ka,
                               float* __restrict__ t_cf){
    int n = *cnt;
    for (int t = blockIdx.x*blockDim.x + threadIdx.x; t < n; t += gridDim.x*blockDim.x){
        int ij = u_ij[t], ik = u_ik[t];
        float rij = elen[ij], rik = elen[ik];
        float cc = polycut(rij)*polycut(rik);
        float ax = evec[ij*3+0], ay = evec[ij*3+1], az = evec[ij*3+2];
        float bx = evec[ik*3+0], by = evec[ik*3+1], bz = evec[ik*3+2];
        float dot = ax*bx + ay*by + az*bz;
        float c = dot/(rij*rik + 1e-12f);
        c = fminf(fmaxf(c, -1.0f + 1e-7f), 1.0f - 1e-7f);
        float a0 = 1.0f, a1 = c, a2 = 2.0f*c*c - 1.0f;
        float x = rik*(PI_F/TBCUT);
        float s1, c1;
        __sincosf(x, &s1, &c1);
        float s2 = 2.0f*s1*c1;
        float s3 = s1*(3.0f - 4.0f*s1*s1);
        float inv = 1.0f/(rik + 1e-6f);
        float r0 = s1*inv, r1 = s2*inv, r2 = s3*inv;
        int pos = atomicAdd(&curs[ij], 1);
        t_ka[pos] = esrc[ik];
        float* d = t_cf + (size_t)pos*SBF;
        d[0] = r0*a0*cc; d[1] = r0*a1*cc; d[2] = r0*a2*cc;
        d[3] = r1*a0*cc; d[4] = r1*a1*cc; d[5] = r1*a2*cc;
        d[6] = r2*a0*cc; d[7] = r2*a1*cc; d[8] = r2*a2*cc;
    }
}

// ---------------- fused per-layer gated blocks (ge + ga), all-MFMA ----------------
// R12-proven config: 64 edges/block, 512 threads, src_s/dst_s index cache in LDS.
// ENC/GM/STORE compile-time. tb(9) per edge computed INLINE from triples CSR.
// Coalesced Eh writeback. NO launch_bounds (R5/R7).
template<int ENC, int GM, int STORE>
__global__
void k_gated_fused(const ushort* __restrict__ Ah, const int* __restrict__ gmap,
                   ushort* __restrict__ Eh,
                   const int* __restrict__ esrc, const int* __restrict__ edst,
                   const float* __restrict__ rbf0,
                   const int* __restrict__ toff, const int* __restrict__ t_ka,
                   const float* __restrict__ t_cf, const float* __restrict__ amlp,
                   const ushort* __restrict__ Wem, const ushort* __restrict__ Weg,
                   const ushort* __restrict__ Wam, const ushort* __restrict__ Wag,
                   const ushort* __restrict__ WxM, const ushort* __restrict__ WxG,
                   const ushort* __restrict__ Ble, const ushort* __restrict__ Bla,
                   const ushort* __restrict__ Bte, const ushort* __restrict__ Benc,
                   const float* __restrict__ btm, const float* __restrict__ btg,
                   const float* __restrict__ bam, const float* __restrict__ bag,
                   const float* __restrict__ tbb, const float* __restrict__ eleb,
                   const float* __restrict__ elab, const float* __restrict__ encb,
                   float* __restrict__ agg){
    __shared__ __align__(16) ushort feat_s[MEDGE*FSTR];
    __shared__ int src_s[MEDGE];
    __shared__ int dst_s[MEDGE];

    const int tid = threadIdx.x;
    const int e0  = blockIdx.x*MEDGE;

    if (tid < MEDGE){
        int e = min(e0 + tid, NEDGE-1);
        src_s[tid] = esrc[e];
        int d = edst[e];
        if (GM && d >= NLOCAL) d = gmap[d - NLOCAL];
        dst_s[tid] = d;
    }
    __syncthreads();

    #pragma unroll
    for (int j = 0; j < 6; j++){
        int idx = j*512 + tid;
        int m   = idx/48;
        int k8  = idx - m*48;
        short8 h;
        if (k8 < 16){
            h = *(const short8*)(Ah + (size_t)src_s[m]*UNITS + k8*8);
        } else if (k8 < 32){
            h = *(const short8*)(Ah + (size_t)dst_s[m]*UNITS + (k8-16)*8);
        } else if (ENC){
            short8 z = {0,0,0,0,0,0,0,0};
            h = z;
        } else {
            int e = min(e0 + m, NEDGE-1);
            h = *(const short8*)(Eh + (size_t)e*UNITS + (k8-32)*8);
        }
        *(short8*)&feat_s[m*FSTR + k8*8] = h;
    }
    if (tid < MEDGE){
        int e = min(e0 + tid, NEDGE-1);
        float tb[SBF];
        #pragma unroll
        for (int s = 0; s < SBF; s++) tb[s] = 0.0f;
        int beg = toff[e], end = toff[e+1];
        for (int t = beg; t < end; t++){
            const float* cf = t_cf + (size_t)t*SBF;
            const float* am = amlp + (size_t)t_ka[t]*SBF;
            #pragma unroll
            for (int s = 0; s < SBF; s++) tb[s] = fmaf(cf[s], am[s], tb[s]);
        }
        ushort row[32];
        #pragma unroll
        for (int k = 0; k < 10; k++) row[k] = f2bf(rbf0[(size_t)e*NRBF + k]);
        #pragma unroll
        for (int s = 0; s < SBF; s++) row[10+s] = f2bf(tb[s]);
        #pragma unroll
        for (int k = 19; k < 32; k++) row[k] = 0;
        #pragma unroll
        for (int j8 = 0; j8 < 4; j8++)
            *(short8*)&feat_s[tid*FSTR + 384 + j8*8] = *(const short8*)&row[j8*8];
    }
    __syncthreads();

    const int lane = tid & 63;
    const int w    = tid >> 6;
    const int quad = lane >> 4;
    const int l15  = lane & 15;
    const int c    = w*16 + l15;

    f32x4 acc_em[4], acc_eg[4], acc_te[4], acc_le[4], acc_en[ENC ? 4 : 1];
    {
        float bm = btm[c], bg = btg[c], tb = tbb[c], le = eleb[c];
        #pragma unroll
        for (int mt = 0; mt < 4; mt++){
            acc_em[mt] = splat4(bm); acc_eg[mt] = splat4(bg);
            acc_te[mt] = splat4(tb); acc_le[mt] = splat4(le);
        }
        if (ENC){
            float eb = encb[c];
            #pragma unroll
            for (int mt = 0; mt < 4; mt++) acc_en[mt] = splat4(eb);
        }
    }
    const ushort* abase = feat_s + l15*FSTR + quad*8;

    for (int ks = 0; ks < 12; ks++){
        short8 a[4];
        #pragma unroll
        for (int mt = 0; mt < 4; mt++)
            a[mt] = *(const short8*)(abase + mt*16*FSTR + ks*32);
        size_t boff = ((size_t)(ks*8 + w)*64 + lane)*8;
        short8 b_em = *(const short8*)(Wem + boff);
        short8 b_eg = *(const short8*)(Weg + boff);
        #pragma unroll
        for (int mt = 0; mt < 4; mt++){
            acc_em[mt] = __builtin_amdgcn_mfma_f32_16x16x32_bf16(a[mt], b_em, acc_em[mt], 0, 0, 0);
            acc_eg[mt] = __builtin_amdgcn_mfma_f32_16x16x32_bf16(a[mt], b_eg, acc_eg[mt], 0, 0, 0);
        }
    }
    {
        size_t bx = ((size_t)w*64 + lane)*8;
        short8 b_xm = *(const short8*)(WxM + bx);
        short8 b_xg = *(const short8*)(WxG + bx);
        short8 b_te = *(const short8*)(Bte + bx);
        short8 b_le = *(const short8*)(Ble + bx);
        #pragma unroll
        for (int mt = 0; mt < 4; mt++){
            short8 ax = *(const short8*)(abase + mt*16*FSTR + 384);
            acc_em[mt] = __builtin_amdgcn_mfma_f32_16x16x32_bf16(ax, b_xm, acc_em[mt], 0, 0, 0);
            acc_eg[mt] = __builtin_amdgcn_mfma_f32_16x16x32_bf16(ax, b_xg, acc_eg[mt], 0, 0, 0);
            acc_te[mt] = __builtin_amdgcn_mfma_f32_16x16x32_bf16(ax, b_te, acc_te[mt], 0, 0, 0);
            acc_le[mt] = __builtin_amdgcn_mfma_f32_16x16x32_bf16(ax, b_le, acc_le[mt], 0, 0, 0);
        }
        if (ENC){
            short8 b_en = *(const short8*)(Benc + bx);
            #pragma unroll
            for (int mt = 0; mt < 4; mt++){
                short8 ax = *(const short8*)(abase + mt*16*FSTR + 384);
                acc_en[mt] = __builtin_amdgcn_mfma_f32_16x16x32_bf16(ax, b_en, acc_en[mt], 0, 0, 0);
            }
        }
    }

    __syncthreads();
    #pragma unroll
    for (int mt = 0; mt < 4; mt++){
        #pragma unroll
        for (int r = 0; r < 4; r++){
            int ml = mt*16 + quad*4 + r;
            int e  = e0 + ml;
            if (e >= NEDGE) continue;
            float gate = gatef(acc_em[mt][r], acc_eg[mt][r]);
            float eold = ENC ? acc_en[mt][r] : bf2f(feat_s[ml*FSTR + 256 + c]);
            float enew = eold + acc_te[mt][r] + gate*acc_le[mt][r];
            feat_s[ml*FSTR + 256 + c] = f2bf(enew);
        }
    }
    __syncthreads();

    if (STORE){
        #pragma unroll
        for (int j = 0; j < 2; j++){
            int idx = j*512 + tid;
            int row = idx >> 4;
            int q8  = idx & 15;
            int e   = e0 + row;
            if (e < NEDGE)
                *(short8*)(Eh + (size_t)e*UNITS + q8*8)
                    = *(const short8*)&feat_s[row*FSTR + 256 + q8*8];
        }
    }

    f32x4 acc_am[4], acc_ag[4], acc_la[4];
    {
        float bm = bam[c], bg = bag[c], lb = elab[c];
        #pragma unroll
        for (int mt = 0; mt < 4; mt++){
            acc_am[mt] = splat4(bm); acc_ag[mt] = splat4(bg); acc_la[mt] = splat4(lb);
        }
    }
    for (int ks = 0; ks < 12; ks++){
        short8 a[4];
        #pragma unroll
        for (int mt = 0; mt < 4; mt++)
            a[mt] = *(const short8*)(abase + mt*16*FSTR + ks*32);
        size_t boff = ((size_t)(ks*8 + w)*64 + lane)*8;
        short8 b_am = *(const short8*)(Wam + boff);
        short8 b_ag = *(const short8*)(Wag + boff);
        #pragma unroll
        for (int mt = 0; mt < 4; mt++){
            acc_am[mt] = __builtin_amdgcn_mfma_f32_16x16x32_bf16(a[mt], b_am, acc_am[mt], 0, 0, 0);
            acc_ag[mt] = __builtin_amdgcn_mfma_f32_16x16x32_bf16(a[mt], b_ag, acc_ag[mt], 0, 0, 0);
        }
    }
    {
        size_t bx = ((size_t)w*64 + lane)*8;
        short8 b_la = *(const short8*)(Bla + bx);
        #pragma unroll
        for (int mt = 0; mt < 4; mt++){
            short8 ax = *(const short8*)(abase + mt*16*FSTR + 384);
            acc_la[mt] = __builtin_amdgcn_mfma_f32_16x16x32_bf16(ax, b_la, acc_la[mt], 0, 0, 0);
        }
    }

    #pragma unroll
    for (int mt = 0; mt < 4; mt++){
        #pragma unroll
        for (int r = 0; r < 4; r++){
            int ml = mt*16 + quad*4 + r;
            int e  = e0 + ml;
            if (e >= NEDGE) continue;
            float gate = gatef(acc_am[mt][r], acc_ag[mt][r]);
            atomicAdd(&agg[(size_t)src_s[ml]*UNITS + c], gate*acc_la[mt][r]);
        }
    }
}

// ---------------- final readout via MFMA ----------------
// 64 atoms/block, 512 threads. A rows bf16 in LDS; W1 pre-packed B-fragments.
// hid in C-layout; dot with W2 via shfl-xor over the 16-lane column group;
// per-row wave partials in LDS; per-atom scale/shift; one atomic per block.
// (Old version re-streamed W1 64KB per atom-pair: ~1.6GB L2 = ~45us L2-bound.)
__global__ void k_final(const float* __restrict__ A, const ushort* __restrict__ Wf,
                        const float* __restrict__ b1, const float* __restrict__ W2,
                        const float* __restrict__ b2, const int* __restrict__ anum,
                        const float* __restrict__ escl, const float* __restrict__ eshf,
                        float* __restrict__ out){
    __shared__ __align__(16) ushort a_s[64*136];   // 64 rows x 128 bf16, stride 136
    __shared__ float osum[64][8];
    const int tid = threadIdx.x;
    const int a0  = blockIdx.x*64;

    // stage: 1024 chunks (row, q8), 2/thread; invalid rows zero (excluded at readout)
    #pragma unroll
    for (int j = 0; j < 2; j++){
        int idx = j*512 + tid;
        int row = idx >> 4;
        int q8  = idx & 15;
        int a   = a0 + row;
        short8 h;
        if (a < NLOCAL){
            const float4* p = (const float4*)(A + (size_t)a*UNITS + q8*8);
            float4 v0 = p[0], v1 = p[1];
            h[0] = (short)f2bf(v0.x); h[1] = (short)f2bf(v0.y);
            h[2] = (short)f2bf(v0.z); h[3] = (short)f2bf(v0.w);
            h[4] = (short)f2bf(v1.x); h[5] = (short)f2bf(v1.y);
            h[6] = (short)f2bf(v1.z); h[7] = (short)f2bf(v1.w);
        } else {
            short8 z = {0,0,0,0,0,0,0,0};
            h = z;
        }
        *(short8*)&a_s[row*136 + q8*8] = h;
    }
    __syncthreads();

    const int lane = tid & 63;
    const int w    = tid >> 6;
    const int quad = lane >> 4;
    const int l15  = lane & 15;
    const int c    = w*16 + l15;

    f32x4 acc[4];
    {
        float bc = b1[c];
        #pragma unroll
        for (int mt = 0; mt < 4; mt++) acc[mt] = splat4(bc);
    }
    const ushort* abase = a_s + l15*136 + quad*8;
    for (int ks = 0; ks < 4; ks++){
        size_t boff = ((size_t)(ks*8 + w)*64 + lane)*8;
        short8 b = *(const short8*)(Wf + boff);
        #pragma unroll
        for (int mt = 0; mt < 4; mt++){
            short8 a = *(const short8*)(abase + mt*16*136 + ks*32);
            acc[mt] = __builtin_amdgcn_mfma_f32_16x16x32_bf16(a, b, acc[mt], 0, 0, 0);
        }
    }
    float w2c = W2[c];
    #pragma unroll
    for (int mt = 0; mt < 4; mt++){
        #pragma unroll
        for (int r = 0; r < 4; r++){
            int row = mt*16 + quad*4 + r;
            float tot = acc[mt][r];
            float hid = tot/(1.0f+__expf(-tot));
            float v = hid*w2c;
            v += __shfl_xor(v, 1);
            v += __shfl_xor(v, 2);
            v += __shfl_xor(v, 4);
            v += __shfl_xor(v, 8);
            if (l15 == 0) osum[row][w] = v;
        }
    }
    __syncthreads();
    if (tid < 64){
        int a = a0 + tid;
        float s = 0.0f;
        #pragma unroll
        for (int ww = 0; ww < 8; ww++) s += osum[tid][ww];
        float part = 0.0f;
        if (a < NLOCAL){
            int z = anum[a];
            part = escl[z]*(s + b2[0]) + eshf[z];
        }
        part += __shfl_xor(part, 1);
        part += __shfl_xor(part, 2);
        part += __shfl_xor(part, 4);
        part += __shfl_xor(part, 8);
        part += __shfl_xor(part, 16);
        part += __shfl_xor(part, 32);
        if (tid == 0) atomicAdd(out, part);
    }
}

extern "C" void kernel_launch(void* const* d_in, const int* in_sizes, int n_in,
                              void* d_out, int out_size, void* d_ws, size_t ws_size,
                              hipStream_t stream){
    const int*   anum  = (const int*)d_in[0];
    const float* pos   = (const float*)d_in[1];
    const float* cell  = (const float*)d_in[2];
    const float* pbc   = (const float*)d_in[3];
    const int*   esrc  = (const int*)d_in[4];
    const int*   edst  = (const int*)d_in[5];
    const int*   tbi   = (const int*)d_in[6];
    const int*   batch = (const int*)d_in[7];
    const int*   gmap  = (const int*)d_in[8];
    const float* embw  = (const float*)d_in[10];
    const float* encw  = (const float*)d_in[11];
    const float* encb  = (const float*)d_in[12];
    const float* tbaw  = (const float*)d_in[13];
    const float* tbab  = (const float*)d_in[14];
    const float* tbgw  = (const float*)d_in[15];
    const float* tbgb  = (const float*)d_in[16];
    const float* gewm  = (const float*)d_in[17];
    const float* gebm  = (const float*)d_in[18];
    const float* gewg  = (const float*)d_in[19];
    const float* gebg  = (const float*)d_in[20];
    const float* elew  = (const float*)d_in[21];
    const float* eleb  = (const float*)d_in[22];
    const float* gawm  = (const float*)d_in[23];
    const float* gabm  = (const float*)d_in[24];
    const float* gawg  = (const float*)d_in[25];
    const float* gabg  = (const float*)d_in[26];
    const float* elaw  = (const float*)d_in[27];
    const float* elab  = (const float*)d_in[28];
    const float* fw1   = (const float*)d_in[29];
    const float* fb1   = (const float*)d_in[30];
    const float* fw2   = (const float*)d_in[31];
    const float* fb2   = (const float*)d_in[32];
    const float* escl  = (const float*)d_in[33];
    const float* eshf  = (const float*)d_in[34];
    (void)in_sizes; (void)n_in; (void)out_size; (void)ws_size;

    float* ws     = (float*)d_ws;
    float* aggA   = ws;                                   // NLOCAL*128 f32
    float* aggB   = aggA   + (size_t)NLOCAL*UNITS;        // NLOCAL*128 f32
    float* evec   = aggB   + (size_t)NLOCAL*UNITS;        // NEDGE*3
    float* elen   = evec   + (size_t)NEDGE*3;             // NEDGE
    float* rbf0   = elen   + (size_t)NEDGE;               // NEDGE*10
    float* amlp   = rbf0   + (size_t)NEDGE*NRBF;          // NLOCAL*9
    float* btot   = amlp   + (size_t)NLOCAL*SBF;          // 3*2*128
    int*   hist   = (int*)(btot + 3*2*128);               // NEDGE
    int*   tcnt   = hist + NEDGE;                         // [0]=cnt [1]=scan-done (zeroed with hist)
    int*   toff   = tcnt + 4;                             // NEDGE+1
    int*   curs   = toff + NEDGE + 1;                     // NEDGE (+pad)
    int*   bsum   = curs + NEDGE + 3;                     // NCHUNK (+pad)
    int*   total  = bsum + NCHUNK + 1;                    // 1 (+pad)
    int*   u_ij   = total + 4;                            // NTRIPLE
    int*   u_ik   = u_ij + NTRIPLE;                       // NTRIPLE
    int*   t_ka   = u_ik + NTRIPLE;                       // NTRIPLE
    float* t_cf   = (float*)(t_ka + NTRIPLE);             // 9*NTRIPLE (AoS)
    ushort* edgeEh = (ushort*)(t_cf + (size_t)9*NTRIPLE); // NEDGE*128 bf16
    ushort* embedAh = edgeEh + (size_t)NEDGE*UNITS;       // NTOTAL*128 bf16
    ushort* aggAh   = embedAh + (size_t)NTOTAL*UNITS;     // NLOCAL*128 bf16
    ushort* wmain  = aggAh + (size_t)NLOCAL*UNITS;        // 3*4*49152
    ushort* wext   = wmain + (size_t)3*4*49152;           // 3*2*4096
    ushort* waux   = wext  + (size_t)3*2*4096;            // 3*3*4096
    ushort* wencb  = waux  + (size_t)3*3*4096;            // 4096
    ushort* wfin   = wencb + 4096;                        // 4*8*64*8 = 16384

    float* out = (float*)d_out;
    hipMemsetAsync(out, 0, sizeof(float), stream);
    hipMemsetAsync(hist, 0, (NEDGE+4)*sizeof(int), stream);   // hist + tcnt + done

    k_prologue<<<PB_ALL, 256, 0, stream>>>(gewm, gewg, gawm, gawg, tbgw, encw,
                                           elew, elaw, gebm, gebg, tbgb, encb, fw1,
                                           pos, cell, pbc, esrc, edst, batch, anum, embw,
                                           wmain, wext, waux, wencb, wfin, btot,
                                           evec, elen, rbf0, embedAh);
    k_triple_pass1<<<(NTRIPLE+255)/256, 256, 0, stream>>>(elen, tbi, tcnt, u_ij, u_ik, hist);
    k_scanAB<<<NCHUNK, 256, 0, stream>>>(hist, toff, bsum, total, tcnt+1);
    k_scanC<<<(NEDGE+255)/256, 256, 0, stream>>>(toff, curs, bsum, total);
    k_triple_pass2<<<256, 256, 0, stream>>>(evec, elen, esrc, tcnt, u_ij, u_ik,
                                            curs, t_ka, t_cf);

    const int gemm_blocks = (NEDGE + MEDGE - 1)/MEDGE;
    float*  Fin[3]  = { nullptr, aggA, aggB };
    float*  Aout[3] = { aggA,    aggB, aggA };
    for (int L = 0; L < NLAYERS; L++){
        const ushort* wmL = wmain + (size_t)L*4*49152;
        const ushort* wxL = wext  + (size_t)L*2*4096;
        const ushort* waL = waux  + (size_t)L*3*4096;
        if (L == 0)
            k_tb_mlp<1,0><<<(NLOCAL+255)/256, 256, 0, stream>>>(nullptr, anum, embw,
                tbaw + (size_t)L*UNITS*SBF, tbab + (size_t)L*SBF, amlp, Aout[L], aggAh);
        else
            k_tb_mlp<0,1><<<(NLOCAL+255)/256, 256, 0, stream>>>(Fin[L], anum, embw,
                tbaw + (size_t)L*UNITS*SBF, tbab + (size_t)L*SBF, amlp, Aout[L], aggAh);
        const ushort* AhL = (L == 0) ? embedAh : aggAh;
        #define GATED_ARGS AhL, gmap, edgeEh, esrc, edst, rbf0, toff, t_ka, t_cf, amlp, \
            wmL + 0*49152, wmL + 1*49152, wmL + 2*49152, wmL + 3*49152, \
            wxL + 0*4096,  wxL + 1*4096, \
            waL + 0*4096,  waL + 1*4096, waL + 2*4096, wencb, \
            btot + (size_t)L*2*128, btot + (size_t)L*2*128 + 128, \
            gabm + (size_t)L*UNITS, gabg + (size_t)L*UNITS, \
            tbgb + (size_t)L*UNITS, eleb + (size_t)L*UNITS, elab + (size_t)L*UNITS, \
            encb, Aout[L]
        if (L == 0)
            k_gated_fused<1,0,1><<<gemm_blocks, 512, 0, stream>>>(GATED_ARGS);
        else if (L == 1)
            k_gated_fused<0,1,1><<<gemm_blocks, 512, 0, stream>>>(GATED_ARGS);
        else
            k_gated_fused<0,1,0><<<gemm_blocks, 512, 0, stream>>>(GATED_ARGS);
        #undef GATED_ARGS
    }
    k_final<<<(NLOCAL+63)/64, 512, 0, stream>>>(aggA, wfin, fb1, fw2, fb2,
                                                anum, escl, eshf, out);
}

// Round 20
// 958.387 us; speedup vs baseline: 1.8435x; 1.0436x over previous
//
#include <hip/hip_runtime.h>
#include <math.h>

#define UNITS   128
#define NRBF    10
#define SBF     9
#define NLAYERS 3
#define NELEM   95
#define NTOTAL  60000
#define NLOCAL  50000
#define NGHOST  10000
#define NEDGE   250000
#define NTRIPLE 1000000
#define CUTOFF  5.0f
#define TBCUT   4.0f
#define PI_F    3.14159265358979323846f
#define FSTR    424   // feat row stride in ushorts: 13 kb * 32 + 8 pad
#define MEDGE   64    // edges per gated block
#define SCHUNK  1024
#define NCHUNK  ((NEDGE + SCHUNK - 1)/SCHUNK)   // 245

// prologue block ranges
#define PB_MAIN 288              // 3*4*12*8*64/256
#define PB_EXT  12
#define PB_AUX  18
#define PB_ENC  2
#define PB_BIAS 3
#define PB_W1   8
#define PB_PACK (PB_MAIN+PB_EXT+PB_AUX+PB_ENC+PB_BIAS+PB_W1)   // 331
#define PB_GEOM 977
#define PB_EMB  7500
#define PB_ALL  (PB_PACK+PB_GEOM+PB_EMB)   // 8808

typedef __attribute__((ext_vector_type(8))) short short8;
typedef __attribute__((ext_vector_type(4))) float f32x4;

__device__ __forceinline__ float sigm(float x){ return 1.0f/(1.0f+__expf(-x)); }
__device__ __forceinline__ float polycut(float r){
    float q = r*(1.0f/TBCUT);
    float q2 = q*q, q3 = q2*q;
    float p = 1.0f - 6.0f*q2*q3 + 15.0f*q2*q2 - 10.0f*q3;
    return (r <= TBCUT) ? p : 0.0f;
}
__device__ __forceinline__ ushort f2bf(float x){
    unsigned u = __float_as_uint(x);
    unsigned r = (u + 0x7fffu + ((u>>16)&1u)) >> 16;
    return (ushort)r;
}
__device__ __forceinline__ float bf2f(ushort h){
    return __uint_as_float(((unsigned)h) << 16);
}
__device__ __forceinline__ f32x4 splat4(float x){ f32x4 v = {x,x,x,x}; return v; }
__device__ __forceinline__ float gatef(float xm, float xg){
    float d = (1.0f+__expf(-xm))*(1.0f+__expf(-xg));
    return xm*__builtin_amdgcn_rcpf(d);
}

// ---------------- mega-prologue: packing + edge geometry + atom embed + zeroing ----------------
__global__ void k_prologue(const float* __restrict__ gewm, const float* __restrict__ gewg,
                           const float* __restrict__ gawm, const float* __restrict__ gawg,
                           const float* __restrict__ tbg,  const float* __restrict__ encw,
                           const float* __restrict__ elew, const float* __restrict__ elaw,
                           const float* __restrict__ gebm, const float* __restrict__ gebg,
                           const float* __restrict__ tbb,  const float* __restrict__ encb,
                           const float* __restrict__ fw1,
                           const float* __restrict__ pos, const float* __restrict__ cell,
                           const float* __restrict__ pbc, const int* __restrict__ esrc,
                           const int* __restrict__ edst, const int* __restrict__ batch,
                           const int* __restrict__ anum, const float* __restrict__ embw,
                           ushort* __restrict__ wmain, ushort* __restrict__ wext,
                           ushort* __restrict__ waux,  ushort* __restrict__ wencb,
                           ushort* __restrict__ wfin,  float* __restrict__ btot,
                           float* __restrict__ evec, float* __restrict__ elen,
                           float* __restrict__ rbf0, ushort* __restrict__ Ah,
                           int* __restrict__ hist, int* __restrict__ tcnt,
                           float* __restrict__ out){
    int blk = blockIdx.x, tid = threadIdx.x;
    if (blk < PB_MAIN){
        int t = blk*256 + tid;
        if (t >= 3*4*12*8*64) return;
        int lane = t & 63;
        int nt   = (t>>6) & 7;
        int rest = t >> 9;
        int kb   = rest % 12;
        int r2   = rest / 12;
        int mat  = r2 & 3;
        int L    = r2 >> 2;
        const float* src;
        if      (mat == 0) src = gewm;
        else if (mat == 1) src = gewg;
        else if (mat == 2) src = gawm;
        else               src = gawg;
        src += (size_t)L*384*128;
        int n = nt*16 + (lane & 15);
        int kbase = kb*32 + (lane>>4)*8;
        ushort* dst = wmain + (size_t)t*8;
        #pragma unroll
        for (int j = 0; j < 8; j++) dst[j] = f2bf(src[(size_t)(kbase+j)*128 + n]);
    } else if (blk < PB_MAIN+PB_EXT){
        int t = (blk-PB_MAIN)*256 + tid;
        if (t >= 3*2*512) return;
        int lane = t & 63;
        int nt   = (t>>6) & 7;
        int mat  = (t>>9) & 1;
        int L    = t >> 10;
        const float* W  = ((mat==0)? gewm : gewg) + (size_t)L*384*128;
        const float* tg = tbg + (size_t)L*SBF*UNITS;
        int n = nt*16 + (lane & 15);
        ushort* dst = wext + (size_t)t*8;
        #pragma unroll
        for (int j = 0; j < 8; j++){
            int k = (lane>>4)*8 + j;
            float v = 0.0f;
            if (k >= 10 && k <= 18){
                int s = k - 10;
                for (int kk = 0; kk < 128; kk++)
                    v = fmaf(tg[s*UNITS+kk], W[(size_t)(256+kk)*128 + n], v);
            } else if (k < 10 && L == 0){
                for (int kk = 0; kk < 128; kk++)
                    v = fmaf(encw[k*UNITS+kk], W[(size_t)(256+kk)*128 + n], v);
            }
            dst[j] = f2bf(v);
        }
    } else if (blk < PB_MAIN+PB_EXT+PB_AUX){
        int t = (blk-PB_MAIN-PB_EXT)*256 + tid;
        if (t >= 3*3*512) return;
        int lane = t & 63;
        int nt   = (t>>6) & 7;
        int rest = t >> 9;
        int mat  = rest % 3;
        int L    = rest / 3;
        int n = nt*16 + (lane & 15);
        ushort* dst = waux + (size_t)t*8;
        #pragma unroll
        for (int j = 0; j < 8; j++){
            int k = (lane>>4)*8 + j;
            float v = 0.0f;
            if (mat == 0){ if (k < 10) v = elew[(size_t)L*NRBF*UNITS + k*UNITS + n]; }
            else if (mat == 1){ if (k < 10) v = elaw[(size_t)L*NRBF*UNITS + k*UNITS + n]; }
            else { if (k >= 10 && k <= 18) v = tbg[(size_t)L*SBF*UNITS + (k-10)*UNITS + n]; }
            dst[j] = f2bf(v);
        }
    } else if (blk < PB_MAIN+PB_EXT+PB_AUX+PB_ENC){
        int t = (blk-PB_MAIN-PB_EXT-PB_AUX)*256 + tid;
        if (t >= 512) return;
        int lane = t & 63;
        int nt   = t >> 6;
        int n = nt*16 + (lane & 15);
        ushort* dst = wencb + (size_t)t*8;
        #pragma unroll
        for (int j = 0; j < 8; j++){
            int k = (lane>>4)*8 + j;
            float v = (k < 10) ? encw[k*UNITS + n] : 0.0f;
            dst[j] = f2bf(v);
        }
    } else if (blk < PB_MAIN+PB_EXT+PB_AUX+PB_ENC+PB_BIAS){
        int t = (blk-PB_MAIN-PB_EXT-PB_AUX-PB_ENC)*256 + tid;
        if (t >= 3*2*128) return;
        int n = t & 127;
        int mat = (t>>7) & 1;
        int L = t >> 8;
        const float* W = ((mat==0)? gewm : gewg) + (size_t)L*384*128;
        const float* be = ((mat==0)? gebm : gebg) + (size_t)L*UNITS;
        const float* tb = tbb + (size_t)L*UNITS;
        float v = be[n];
        for (int kk = 0; kk < 128; kk++){
            float f = tb[kk];
            if (L == 0) f += encb[kk];
            v = fmaf(f, W[(size_t)(256+kk)*128 + n], v);
        }
        btot[t] = v;
    } else if (blk < PB_PACK){
        int t = (blk-PB_MAIN-PB_EXT-PB_AUX-PB_ENC-PB_BIAS)*256 + tid;
        if (t >= 4*8*64) return;
        int lane = t & 63;
        int nt   = (t>>6) & 7;
        int kb   = t >> 9;
        int n = nt*16 + (lane & 15);
        int kbase = kb*32 + (lane>>4)*8;
        ushort* dst = wfin + (size_t)t*8;
        #pragma unroll
        for (int j = 0; j < 8; j++) dst[j] = f2bf(fw1[(size_t)(kbase+j)*128 + n]);
    } else if (blk < PB_PACK+PB_GEOM){
        // zero counters (first geom block) + per-edge: hist=0, geometry, rbf
        if (blk == PB_PACK && tid < 4) tcnt[tid] = 0;
        if (blk == PB_PACK && tid == 4) out[0] = 0.0f;
        int e = (blk-PB_PACK)*256 + tid;
        if (e >= NEDGE) return;
        hist[e] = 0;
        int s = esrc[e], d = edst[e];
        int b = batch[s];
        const float* C = cell + b*9;
        float p0 = pbc[e*3+0], p1 = pbc[e*3+1], p2 = pbc[e*3+2];
        float vx = pos[s*3+0] - (pos[d*3+0] + p0*C[0] + p1*C[3] + p2*C[6]);
        float vy = pos[s*3+1] - (pos[d*3+1] + p0*C[1] + p1*C[4] + p2*C[7]);
        float vz = pos[s*3+2] - (pos[d*3+2] + p0*C[2] + p1*C[5] + p2*C[8]);
        float r = sqrtf(vx*vx + vy*vy + vz*vz);
        evec[e*3+0] = vx; evec[e*3+1] = vy; evec[e*3+2] = vz;
        elen[e] = r;
        #pragma unroll
        for (int i = 0; i < NRBF; i++){
            float mu = (CUTOFF/(NRBF-1))*i;
            float dm = r - mu;
            rbf0[e*NRBF + i] = __expf(-dm*dm*2.0f);
        }
    } else {
        int t = (blk-PB_PACK-PB_GEOM)*256 + tid;
        if (t >= NTOTAL*32) return;
        int a = t >> 5, q = t & 31;
        float4 v = ((const float4*)embw)[anum[a]*32 + q];
        ushort4 h;
        h.x = f2bf(v.x); h.y = f2bf(v.y); h.z = f2bf(v.z); h.w = f2bf(v.w);
        ((ushort4*)Ah)[t] = h;
    }
}

// ---------------- per-layer: atom sbf mlp ----------------
// GATHER=1 (L0): read embw[anum[a]] directly, write f32 seed into agg (residual base).
// GATHER=0 (L>=1): read agg in place, write bf16 mirror only (gated adds into agg in place;
// gated reads atom features ONLY through the bf16 mirror, so no aliasing hazard).
template<int GATHER>
__global__ void k_tb_mlp(const int* __restrict__ anum, const float* __restrict__ embw,
                         const float* __restrict__ W, const float* __restrict__ b,
                         float* __restrict__ out, float* __restrict__ agg,
                         ushort* __restrict__ Ah){
    int a = blockIdx.x*blockDim.x + threadIdx.x;
    if (a >= NLOCAL) return;
    float acc[SBF];
    #pragma unroll
    for (int s = 0; s < SBF; s++) acc[s] = b[s];
    const float4* row4 = GATHER ? (const float4*)(embw + (size_t)anum[a]*UNITS)
                                : (const float4*)(agg + (size_t)a*UNITS);
    float4* agg4 = (float4*)(agg + (size_t)a*UNITS);
    ushort4* ah4 = (ushort4*)(Ah + (size_t)a*UNITS);
    for (int k4 = 0; k4 < 32; k4++){
        float4 v = row4[k4];
        if (GATHER){
            agg4[k4] = v;
        } else {
            ushort4 h;
            h.x = f2bf(v.x); h.y = f2bf(v.y); h.z = f2bf(v.z); h.w = f2bf(v.w);
            ah4[k4] = h;
        }
        const float* w = W + (k4*4)*SBF;
        #pragma unroll
        for (int s = 0; s < SBF; s++){
            acc[s] = fmaf(v.x, w[s],        acc[s]);
            acc[s] = fmaf(v.y, w[s+SBF],    acc[s]);
            acc[s] = fmaf(v.z, w[s+2*SBF],  acc[s]);
            acc[s] = fmaf(v.w, w[s+3*SBF],  acc[s]);
        }
    }
    #pragma unroll
    for (int s = 0; s < SBF; s++) out[a*SBF + s] = sigm(acc[s]);
}

// ---------------- triples: single 1M pass (validity + append + hist) ----------------
__global__ void k_triple_pass1(const float* __restrict__ elen, const int* __restrict__ tbi,
                               int* __restrict__ cnt, int* __restrict__ u_ij,
                               int* __restrict__ u_ik, int* __restrict__ hist){
    int t = blockIdx.x*blockDim.x + threadIdx.x;
    int tc = min(t, NTRIPLE-1);
    int ij = tbi[2*tc], ik = tbi[2*tc+1];
    bool valid = (t < NTRIPLE) && (polycut(elen[ij])*polycut(elen[ik]) != 0.0f);

    __shared__ int wbase[4];
    __shared__ int gbase;
    int tid = threadIdx.x;
    int wid = tid >> 6, lid = tid & 63;
    unsigned long long m = __ballot(valid);
    int wpre = __popcll(m & ((1ull << lid) - 1ull));
    if (lid == 0) wbase[wid] = __popcll(m);
    __syncthreads();
    if (tid == 0){
        int s = 0;
        #pragma unroll
        for (int i = 0; i < 4; i++){ int v = wbase[i]; wbase[i] = s; s += v; }
        gbase = (s > 0) ? atomicAdd(cnt, s) : 0;
    }
    __syncthreads();
    if (valid){
        int idx = gbase + wbase[wid] + wpre;
        u_ij[idx] = ij;
        u_ik[idx] = ik;
        atomicAdd(&hist[ij], 1);
    }
}
// fused scanA+scanB: per-chunk LDS scan; last block (done-counter) scans chunk totals
__global__ void k_scanAB(const int* __restrict__ hist, int* __restrict__ toff,
                         int* __restrict__ bsum, int* __restrict__ total,
                         int* __restrict__ done){
    __shared__ int sh[256];
    __shared__ int amlast;
    int b = blockIdx.x, tid = threadIdx.x;
    int base = b*SCHUNK + tid*4;
    int v0 = 0, v1 = 0, v2 = 0, v3 = 0;
    if (base+0 < NEDGE) v0 = hist[base+0];
    if (base+1 < NEDGE) v1 = hist[base+1];
    if (base+2 < NEDGE) v2 = hist[base+2];
    if (base+3 < NEDGE) v3 = hist[base+3];
    int tsum = v0+v1+v2+v3;
    sh[tid] = tsum;
    __syncthreads();
    for (int off = 1; off < 256; off <<= 1){
        int x = (tid >= off) ? sh[tid-off] : 0;
        __syncthreads();
        sh[tid] += x;
        __syncthreads();
    }
    int run = (tid == 0) ? 0 : sh[tid-1];
    if (base+0 < NEDGE) toff[base+0] = run; run += v0;
    if (base+1 < NEDGE) toff[base+1] = run; run += v1;
    if (base+2 < NEDGE) toff[base+2] = run; run += v2;
    if (base+3 < NEDGE) toff[base+3] = run;
    if (tid == 255){
        bsum[b] = sh[255];
        __threadfence();
        amlast = (atomicAdd(done, 1) == gridDim.x - 1);
    }
    __syncthreads();
    if (amlast){
        __threadfence();
        int v = (tid < NCHUNK) ? bsum[tid] : 0;
        __syncthreads();
        sh[tid] = v;
        __syncthreads();
        for (int off = 1; off < 256; off <<= 1){
            int x = (tid >= off) ? sh[tid-off] : 0;
            __syncthreads();
            sh[tid] += x;
            __syncthreads();
        }
        if (tid < NCHUNK) bsum[tid] = sh[tid] - v;
        if (tid == 255) *total = sh[255];
    }
}
__global__ void k_scanC(int* __restrict__ toff, int* __restrict__ curs,
                        const int* __restrict__ bsum, const int* __restrict__ total){
    int i = blockIdx.x*blockDim.x + threadIdx.x;
    if (i < NEDGE){
        int v = toff[i] + bsum[i/SCHUNK];
        toff[i] = v;
        curs[i] = v;
    }
    if (i == 0) toff[NEDGE] = *total;
}
__global__ void k_triple_pass2(const float* __restrict__ evec, const float* __restrict__ elen,
                               const int* __restrict__ esrc, const int* __restrict__ cnt,
                               const int* __restrict__ u_ij, const int* __restrict__ u_ik,
                               int* __restrict__ curs, int* __restrict__ t_ka,
                               float* __restrict__ t_cf){
    int n = *cnt;
    for (int t = blockIdx.x*blockDim.x + threadIdx.x; t < n; t += gridDim.x*blockDim.x){
        int ij = u_ij[t], ik = u_ik[t];
        float rij = elen[ij], rik = elen[ik];
        float cc = polycut(rij)*polycut(rik);
        float ax = evec[ij*3+0], ay = evec[ij*3+1], az = evec[ij*3+2];
        float bx = evec[ik*3+0], by = evec[ik*3+1], bz = evec[ik*3+2];
        float dot = ax*bx + ay*by + az*bz;
        float c = dot/(rij*rik + 1e-12f);
        c = fminf(fmaxf(c, -1.0f + 1e-7f), 1.0f - 1e-7f);
        float a0 = 1.0f, a1 = c, a2 = 2.0f*c*c - 1.0f;
        float x = rik*(PI_F/TBCUT);
        float s1, c1;
        __sincosf(x, &s1, &c1);
        float s2 = 2.0f*s1*c1;
        float s3 = s1*(3.0f - 4.0f*s1*s1);
        float inv = 1.0f/(rik + 1e-6f);
        float r0 = s1*inv, r1 = s2*inv, r2 = s3*inv;
        int pos = atomicAdd(&curs[ij], 1);
        t_ka[pos] = esrc[ik];
        float* d = t_cf + (size_t)pos*SBF;
        d[0] = r0*a0*cc; d[1] = r0*a1*cc; d[2] = r0*a2*cc;
        d[3] = r1*a0*cc; d[4] = r1*a1*cc; d[5] = r1*a2*cc;
        d[6] = r2*a0*cc; d[7] = r2*a1*cc; d[8] = r2*a2*cc;
    }
}

// ---------------- fused per-layer gated blocks (ge + ga), all-MFMA ----------------
// R12-proven config: 64 edges/block, 512 threads, src_s/dst_s index cache in LDS.
// ENC/GM/STORE compile-time. tb(9) per edge INLINE from triples CSR. NO launch_bounds.
template<int ENC, int GM, int STORE>
__global__
void k_gated_fused(const ushort* __restrict__ Ah, const int* __restrict__ gmap,
                   ushort* __restrict__ Eh,
                   const int* __restrict__ esrc, const int* __restrict__ edst,
                   const float* __restrict__ rbf0,
                   const int* __restrict__ toff, const int* __restrict__ t_ka,
                   const float* __restrict__ t_cf, const float* __restrict__ amlp,
                   const ushort* __restrict__ Wem, const ushort* __restrict__ Weg,
                   const ushort* __restrict__ Wam, const ushort* __restrict__ Wag,
                   const ushort* __restrict__ WxM, const ushort* __restrict__ WxG,
                   const ushort* __restrict__ Ble, const ushort* __restrict__ Bla,
                   const ushort* __restrict__ Bte, const ushort* __restrict__ Benc,
                   const float* __restrict__ btm, const float* __restrict__ btg,
                   const float* __restrict__ bam, const float* __restrict__ bag,
                   const float* __restrict__ tbb, const float* __restrict__ eleb,
                   const float* __restrict__ elab, const float* __restrict__ encb,
                   float* __restrict__ agg){
    __shared__ __align__(16) ushort feat_s[MEDGE*FSTR];
    __shared__ int src_s[MEDGE];
    __shared__ int dst_s[MEDGE];

    const int tid = threadIdx.x;
    const int e0  = blockIdx.x*MEDGE;

    if (tid < MEDGE){
        int e = min(e0 + tid, NEDGE-1);
        src_s[tid] = esrc[e];
        int d = edst[e];
        if (GM && d >= NLOCAL) d = gmap[d - NLOCAL];
        dst_s[tid] = d;
    }
    __syncthreads();

    #pragma unroll
    for (int j = 0; j < 6; j++){
        int idx = j*512 + tid;
        int m   = idx/48;
        int k8  = idx - m*48;
        short8 h;
        if (k8 < 16){
            h = *(const short8*)(Ah + (size_t)src_s[m]*UNITS + k8*8);
        } else if (k8 < 32){
            h = *(const short8*)(Ah + (size_t)dst_s[m]*UNITS + (k8-16)*8);
        } else if (ENC){
            short8 z = {0,0,0,0,0,0,0,0};
            h = z;
        } else {
            int e = min(e0 + m, NEDGE-1);
            h = *(const short8*)(Eh + (size_t)e*UNITS + (k8-32)*8);
        }
        *(short8*)&feat_s[m*FSTR + k8*8] = h;
    }
    if (tid < MEDGE){
        int e = min(e0 + tid, NEDGE-1);
        float tb[SBF];
        #pragma unroll
        for (int s = 0; s < SBF; s++) tb[s] = 0.0f;
        int beg = toff[e], end = toff[e+1];
        for (int t = beg; t < end; t++){
            const float* cf = t_cf + (size_t)t*SBF;
            const float* am = amlp + (size_t)t_ka[t]*SBF;
            #pragma unroll
            for (int s = 0; s < SBF; s++) tb[s] = fmaf(cf[s], am[s], tb[s]);
        }
        ushort row[32];
        #pragma unroll
        for (int k = 0; k < 10; k++) row[k] = f2bf(rbf0[(size_t)e*NRBF + k]);
        #pragma unroll
        for (int s = 0; s < SBF; s++) row[10+s] = f2bf(tb[s]);
        #pragma unroll
        for (int k = 19; k < 32; k++) row[k] = 0;
        #pragma unroll
        for (int j8 = 0; j8 < 4; j8++)
            *(short8*)&feat_s[tid*FSTR + 384 + j8*8] = *(const short8*)&row[j8*8];
    }
    __syncthreads();

    const int lane = tid & 63;
    const int w    = tid >> 6;
    const int quad = lane >> 4;
    const int l15  = lane & 15;
    const int c    = w*16 + l15;

    f32x4 acc_em[4], acc_eg[4], acc_te[4], acc_le[4], acc_en[ENC ? 4 : 1];
    {
        float bm = btm[c], bg = btg[c], tb = tbb[c], le = eleb[c];
        #pragma unroll
        for (int mt = 0; mt < 4; mt++){
            acc_em[mt] = splat4(bm); acc_eg[mt] = splat4(bg);
            acc_te[mt] = splat4(tb); acc_le[mt] = splat4(le);
        }
        if (ENC){
            float eb = encb[c];
            #pragma unroll
            for (int mt = 0; mt < 4; mt++) acc_en[mt] = splat4(eb);
        }
    }
    const ushort* abase = feat_s + l15*FSTR + quad*8;

    for (int ks = 0; ks < 12; ks++){
        short8 a[4];
        #pragma unroll
        for (int mt = 0; mt < 4; mt++)
            a[mt] = *(const short8*)(abase + mt*16*FSTR + ks*32);
        size_t boff = ((size_t)(ks*8 + w)*64 + lane)*8;
        short8 b_em = *(const short8*)(Wem + boff);
        short8 b_eg = *(const short8*)(Weg + boff);
        #pragma unroll
        for (int mt = 0; mt < 4; mt++){
            acc_em[mt] = __builtin_amdgcn_mfma_f32_16x16x32_bf16(a[mt], b_em, acc_em[mt], 0, 0, 0);
            acc_eg[mt] = __builtin_amdgcn_mfma_f32_16x16x32_bf16(a[mt], b_eg, acc_eg[mt], 0, 0, 0);
        }
    }
    {
        size_t bx = ((size_t)w*64 + lane)*8;
        short8 b_xm = *(const short8*)(WxM + bx);
        short8 b_xg = *(const short8*)(WxG + bx);
        short8 b_te = *(const short8*)(Bte + bx);
        short8 b_le = *(const short8*)(Ble + bx);
        #pragma unroll
        for (int mt = 0; mt < 4; mt++){
            short8 ax = *(const short8*)(abase + mt*16*FSTR + 384);
            acc_em[mt] = __builtin_amdgcn_mfma_f32_16x16x32_bf16(ax, b_xm, acc_em[mt], 0, 0, 0);
            acc_eg[mt] = __builtin_amdgcn_mfma_f32_16x16x32_bf16(ax, b_xg, acc_eg[mt], 0, 0, 0);
            acc_te[mt] = __builtin_amdgcn_mfma_f32_16x16x32_bf16(ax, b_te, acc_te[mt], 0, 0, 0);
            acc_le[mt] = __builtin_amdgcn_mfma_f32_16x16x32_bf16(ax, b_le, acc_le[mt], 0, 0, 0);
        }
        if (ENC){
            short8 b_en = *(const short8*)(Benc + bx);
            #pragma unroll
            for (int mt = 0; mt < 4; mt++){
                short8 ax = *(const short8*)(abase + mt*16*FSTR + 384);
                acc_en[mt] = __builtin_amdgcn_mfma_f32_16x16x32_bf16(ax, b_en, acc_en[mt], 0, 0, 0);
            }
        }
    }

    __syncthreads();
    #pragma unroll
    for (int mt = 0; mt < 4; mt++){
        #pragma unroll
        for (int r = 0; r < 4; r++){
            int ml = mt*16 + quad*4 + r;
            int e  = e0 + ml;
            if (e >= NEDGE) continue;
            float gate = gatef(acc_em[mt][r], acc_eg[mt][r]);
            float eold = ENC ? acc_en[mt][r] : bf2f(feat_s[ml*FSTR + 256 + c]);
            float enew = eold + acc_te[mt][r] + gate*acc_le[mt][r];
            feat_s[ml*FSTR + 256 + c] = f2bf(enew);
        }
    }
    __syncthreads();

    if (STORE){
        #pragma unroll
        for (int j = 0; j < 2; j++){
            int idx = j*512 + tid;
            int row = idx >> 4;
            int q8  = idx & 15;
            int e   = e0 + row;
            if (e < NEDGE)
                *(short8*)(Eh + (size_t)e*UNITS + q8*8)
                    = *(const short8*)&feat_s[row*FSTR + 256 + q8*8];
        }
    }

    f32x4 acc_am[4], acc_ag[4], acc_la[4];
    {
        float bm = bam[c], bg = bag[c], lb = elab[c];
        #pragma unroll
        for (int mt = 0; mt < 4; mt++){
            acc_am[mt] = splat4(bm); acc_ag[mt] = splat4(bg); acc_la[mt] = splat4(lb);
        }
    }
    for (int ks = 0; ks < 12; ks++){
        short8 a[4];
        #pragma unroll
        for (int mt = 0; mt < 4; mt++)
            a[mt] = *(const short8*)(abase + mt*16*FSTR + ks*32);
        size_t boff = ((size_t)(ks*8 + w)*64 + lane)*8;
        short8 b_am = *(const short8*)(Wam + boff);
        short8 b_ag = *(const short8*)(Wag + boff);
        #pragma unroll
        for (int mt = 0; mt < 4; mt++){
            acc_am[mt] = __builtin_amdgcn_mfma_f32_16x16x32_bf16(a[mt], b_am, acc_am[mt], 0, 0, 0);
            acc_ag[mt] = __builtin_amdgcn_mfma_f32_16x16x32_bf16(a[mt], b_ag, acc_ag[mt], 0, 0, 0);
        }
    }
    {
        size_t bx = ((size_t)w*64 + lane)*8;
        short8 b_la = *(const short8*)(Bla + bx);
        #pragma unroll
        for (int mt = 0; mt < 4; mt++){
            short8 ax = *(const short8*)(abase + mt*16*FSTR + 384);
            acc_la[mt] = __builtin_amdgcn_mfma_f32_16x16x32_bf16(ax, b_la, acc_la[mt], 0, 0, 0);
        }
    }

    #pragma unroll
    for (int mt = 0; mt < 4; mt++){
        #pragma unroll
        for (int r = 0; r < 4; r++){
            int ml = mt*16 + quad*4 + r;
            int e  = e0 + ml;
            if (e >= NEDGE) continue;
            float gate = gatef(acc_am[mt][r], acc_ag[mt][r]);
            atomicAdd(&agg[(size_t)src_s[ml]*UNITS + c], gate*acc_la[mt][r]);
        }
    }
}

// ---------------- final readout via MFMA ----------------
__global__ void k_final(const float* __restrict__ A, const ushort* __restrict__ Wf,
                        const float* __restrict__ b1, const float* __restrict__ W2,
                        const float* __restrict__ b2, const int* __restrict__ anum,
                        const float* __restrict__ escl, const float* __restrict__ eshf,
                        float* __restrict__ out){
    __shared__ __align__(16) ushort a_s[64*136];
    __shared__ float osum[64][8];
    const int tid = threadIdx.x;
    const int a0  = blockIdx.x*64;

    #pragma unroll
    for (int j = 0; j < 2; j++){
        int idx = j*512 + tid;
        int row = idx >> 4;
        int q8  = idx & 15;
        int a   = a0 + row;
        short8 h;
        if (a < NLOCAL){
            const float4* p = (const float4*)(A + (size_t)a*UNITS + q8*8);
            float4 v0 = p[0], v1 = p[1];
            h[0] = (short)f2bf(v0.x); h[1] = (short)f2bf(v0.y);
            h[2] = (short)f2bf(v0.z); h[3] = (short)f2bf(v0.w);
            h[4] = (short)f2bf(v1.x); h[5] = (short)f2bf(v1.y);
            h[6] = (short)f2bf(v1.z); h[7] = (short)f2bf(v1.w);
        } else {
            short8 z = {0,0,0,0,0,0,0,0};
            h = z;
        }
        *(short8*)&a_s[row*136 + q8*8] = h;
    }
    __syncthreads();

    const int lane = tid & 63;
    const int w    = tid >> 6;
    const int quad = lane >> 4;
    const int l15  = lane & 15;
    const int c    = w*16 + l15;

    f32x4 acc[4];
    {
        float bc = b1[c];
        #pragma unroll
        for (int mt = 0; mt < 4; mt++) acc[mt] = splat4(bc);
    }
    const ushort* abase = a_s + l15*136 + quad*8;
    for (int ks = 0; ks < 4; ks++){
        size_t boff = ((size_t)(ks*8 + w)*64 + lane)*8;
        short8 b = *(const short8*)(Wf + boff);
        #pragma unroll
        for (int mt = 0; mt < 4; mt++){
            short8 a = *(const short8*)(abase + mt*16*136 + ks*32);
            acc[mt] = __builtin_amdgcn_mfma_f32_16x16x32_bf16(a, b, acc[mt], 0, 0, 0);
        }
    }
    float w2c = W2[c];
    #pragma unroll
    for (int mt = 0; mt < 4; mt++){
        #pragma unroll
        for (int r = 0; r < 4; r++){
            int row = mt*16 + quad*4 + r;
            float tot = acc[mt][r];
            float hid = tot/(1.0f+__expf(-tot));
            float v = hid*w2c;
            v += __shfl_xor(v, 1);
            v += __shfl_xor(v, 2);
            v += __shfl_xor(v, 4);
            v += __shfl_xor(v, 8);
            if (l15 == 0) osum[row][w] = v;
        }
    }
    __syncthreads();
    if (tid < 64){
        int a = a0 + tid;
        float s = 0.0f;
        #pragma unroll
        for (int ww = 0; ww < 8; ww++) s += osum[tid][ww];
        float part = 0.0f;
        if (a < NLOCAL){
            int z = anum[a];
            part = escl[z]*(s + b2[0]) + eshf[z];
        }
        part += __shfl_xor(part, 1);
        part += __shfl_xor(part, 2);
        part += __shfl_xor(part, 4);
        part += __shfl_xor(part, 8);
        part += __shfl_xor(part, 16);
        part += __shfl_xor(part, 32);
        if (tid == 0) atomicAdd(out, part);
    }
}

extern "C" void kernel_launch(void* const* d_in, const int* in_sizes, int n_in,
                              void* d_out, int out_size, void* d_ws, size_t ws_size,
                              hipStream_t stream){
    const int*   anum  = (const int*)d_in[0];
    const float* pos   = (const float*)d_in[1];
    const float* cell  = (const float*)d_in[2];
    const float* pbc   = (const float*)d_in[3];
    const int*   esrc  = (const int*)d_in[4];
    const int*   edst  = (const int*)d_in[5];
    const int*   tbi   = (const int*)d_in[6];
    const int*   batch = (const int*)d_in[7];
    const int*   gmap  = (const int*)d_in[8];
    const float* embw  = (const float*)d_in[10];
    const float* encw  = (const float*)d_in[11];
    const float* encb  = (const float*)d_in[12];
    const float* tbaw  = (const float*)d_in[13];
    const float* tbab  = (const float*)d_in[14];
    const float* tbgw  = (const float*)d_in[15];
    const float* tbgb  = (const float*)d_in[16];
    const float* gewm  = (const float*)d_in[17];
    const float* gebm  = (const float*)d_in[18];
    const float* gewg  = (const float*)d_in[19];
    const float* gebg  = (const float*)d_in[20];
    const float* elew  = (const float*)d_in[21];
    const float* eleb  = (const float*)d_in[22];
    const float* gawm  = (const float*)d_in[23];
    const float* gabm  = (const float*)d_in[24];
    const float* gawg  = (const float*)d_in[25];
    const float* gabg  = (const float*)d_in[26];
    const float* elaw  = (const float*)d_in[27];
    const float* elab  = (const float*)d_in[28];
    const float* fw1   = (const float*)d_in[29];
    const float* fb1   = (const float*)d_in[30];
    const float* fw2   = (const float*)d_in[31];
    const float* fb2   = (const float*)d_in[32];
    const float* escl  = (const float*)d_in[33];
    const float* eshf  = (const float*)d_in[34];
    (void)in_sizes; (void)n_in; (void)out_size; (void)ws_size;

    float* ws     = (float*)d_ws;
    float* aggA   = ws;                                   // NLOCAL*128 f32 (in-place residual)
    float* evec   = aggA   + (size_t)NLOCAL*UNITS;        // NEDGE*3
    float* elen   = evec   + (size_t)NEDGE*3;             // NEDGE
    float* rbf0   = elen   + (size_t)NEDGE;               // NEDGE*10
    float* amlp   = rbf0   + (size_t)NEDGE*NRBF;          // NLOCAL*9
    float* btot   = amlp   + (size_t)NLOCAL*SBF;          // 3*2*128
    int*   hist   = (int*)(btot + 3*2*128);               // NEDGE
    int*   tcnt   = hist + NEDGE;                         // [0]=cnt [1]=scan-done (zeroed in prologue)
    int*   toff   = tcnt + 4;                             // NEDGE+1
    int*   curs   = toff + NEDGE + 1;                     // NEDGE (+pad)
    int*   bsum   = curs + NEDGE + 3;                     // NCHUNK (+pad)
    int*   total  = bsum + NCHUNK + 1;                    // 1 (+pad)
    int*   u_ij   = total + 4;                            // NTRIPLE
    int*   u_ik   = u_ij + NTRIPLE;                       // NTRIPLE
    int*   t_ka   = u_ik + NTRIPLE;                       // NTRIPLE
    float* t_cf   = (float*)(t_ka + NTRIPLE);             // 9*NTRIPLE (AoS)
    ushort* edgeEh = (ushort*)(t_cf + (size_t)9*NTRIPLE); // NEDGE*128 bf16
    ushort* embedAh = edgeEh + (size_t)NEDGE*UNITS;       // NTOTAL*128 bf16
    ushort* aggAh   = embedAh + (size_t)NTOTAL*UNITS;     // NLOCAL*128 bf16
    ushort* wmain  = aggAh + (size_t)NLOCAL*UNITS;        // 3*4*49152
    ushort* wext   = wmain + (size_t)3*4*49152;           // 3*2*4096
    ushort* waux   = wext  + (size_t)3*2*4096;            // 3*3*4096
    ushort* wencb  = waux  + (size_t)3*3*4096;            // 4096
    ushort* wfin   = wencb + 4096;                        // 16384

    float* out = (float*)d_out;

    k_prologue<<<PB_ALL, 256, 0, stream>>>(gewm, gewg, gawm, gawg, tbgw, encw,
                                           elew, elaw, gebm, gebg, tbgb, encb, fw1,
                                           pos, cell, pbc, esrc, edst, batch, anum, embw,
                                           wmain, wext, waux, wencb, wfin, btot,
                                           evec, elen, rbf0, embedAh,
                                           hist, tcnt, out);
    k_triple_pass1<<<(NTRIPLE+255)/256, 256, 0, stream>>>(elen, tbi, tcnt, u_ij, u_ik, hist);
    k_scanAB<<<NCHUNK, 256, 0, stream>>>(hist, toff, bsum, total, tcnt+1);
    k_scanC<<<(NEDGE+255)/256, 256, 0, stream>>>(toff, curs, bsum, total);
    k_triple_pass2<<<256, 256, 0, stream>>>(evec, elen, esrc, tcnt, u_ij, u_ik,
                                            curs, t_ka, t_cf);

    const int gemm_blocks = (NEDGE + MEDGE - 1)/MEDGE;
    for (int L = 0; L < NLAYERS; L++){
        const ushort* wmL = wmain + (size_t)L*4*49152;
        const ushort* wxL = wext  + (size_t)L*2*4096;
        const ushort* waL = waux  + (size_t)L*3*4096;
        if (L == 0)
            k_tb_mlp<1><<<(NLOCAL+255)/256, 256, 0, stream>>>(anum, embw,
                tbaw + (size_t)L*UNITS*SBF, tbab + (size_t)L*SBF, amlp, aggA, aggAh);
        else
            k_tb_mlp<0><<<(NLOCAL+255)/256, 256, 0, stream>>>(anum, embw,
                tbaw + (size_t)L*UNITS*SBF, tbab + (size_t)L*SBF, amlp, aggA, aggAh);
        const ushort* AhL = (L == 0) ? embedAh : aggAh;
        #define GATED_ARGS AhL, gmap, edgeEh, esrc, edst, rbf0, toff, t_ka, t_cf, amlp, \
            wmL + 0*49152, wmL + 1*49152, wmL + 2*49152, wmL + 3*49152, \
            wxL + 0*4096,  wxL + 1*4096, \
            waL + 0*4096,  waL + 1*4096, waL + 2*4096, wencb, \
            btot + (size_t)L*2*128, btot + (size_t)L*2*128 + 128, \
            gabm + (size_t)L*UNITS, gabg + (size_t)L*UNITS, \
            tbgb + (size_t)L*UNITS, eleb + (size_t)L*UNITS, elab + (size_t)L*UNITS, \
            encb, aggA
        if (L == 0)
            k_gated_fused<1,0,1><<<gemm_blocks, 512, 0, stream>>>(GATED_ARGS);
        else if (L == 1)
            k_gated_fused<0,1,1><<<gemm_blocks, 512, 0, stream>>>(GATED_ARGS);
        else
            k_gated_fused<0,1,0><<<gemm_blocks, 512, 0, stream>>>(GATED_ARGS);
        #undef GATED_ARGS
    }
    k_final<<<(NLOCAL+63)/64, 512, 0, stream>>>(aggA, wfin, fb1, fw2, fb2,
                                                anum, escl, eshf, out);
}